// Round 9
// baseline (528.473 us; speedup 1.0000x reference)
//
#include <hip/hip_runtime.h>
#include <hip/hip_bf16.h>
#include <stdint.h>

typedef __bf16 bf16;
typedef __bf16 bf16x8 __attribute__((ext_vector_type(8)));
typedef __bf16 bf16x4 __attribute__((ext_vector_type(4)));
typedef float  f32x4  __attribute__((ext_vector_type(4)));

#define GLOAD16(gsrc, ldst)                                                        \
  __builtin_amdgcn_global_load_lds(                                               \
      (const __attribute__((address_space(1))) void*)(gsrc),                      \
      (__attribute__((address_space(3))) void*)(ldst), 16, 0, 0)

__device__ __forceinline__ float gelu_f(float v) {
  return 0.5f * v * (1.0f + erff(v * 0.70710678118654752f));
}

// ---- batched transpose+cast for all 8 weights  +  fused ln0 (blocks >= 13824) ----
__global__ __launch_bounds__(256) void transpose_all_k(
    const float* __restrict__ qw0, bf16* __restrict__ qt0,
    const float* __restrict__ pw0, bf16* __restrict__ pt0,
    const float* __restrict__ w10, bf16* __restrict__ t10,
    const float* __restrict__ w20, bf16* __restrict__ t20,
    const float* __restrict__ qw1, bf16* __restrict__ qt1,
    const float* __restrict__ pw1, bf16* __restrict__ pt1,
    const float* __restrict__ w11, bf16* __restrict__ t11,
    const float* __restrict__ w21, bf16* __restrict__ t21,
    const float* __restrict__ x, const float* __restrict__ lng,
    const float* __restrict__ lnb, bf16* __restrict__ lnout) {
  int i = blockIdx.x;
  if (i >= 13824) {
    // ---- ln0: LN(x) -> lnout, 4 tokens/block ----
    const int token = (i - 13824) * 4 + (threadIdx.x >> 6);
    const int lane  = threadIdx.x & 63;
    const float4* xp = (const float4*)(x + (size_t)token * 768);
    float4 v[3];
    float s = 0.f, ss = 0.f;
#pragma unroll
    for (int j = 0; j < 3; j++) {
      v[j] = xp[lane + j * 64];
      s  += v[j].x + v[j].y + v[j].z + v[j].w;
      ss += v[j].x * v[j].x + v[j].y * v[j].y + v[j].z * v[j].z + v[j].w * v[j].w;
    }
#pragma unroll
    for (int o = 32; o > 0; o >>= 1) { s += __shfl_xor(s, o); ss += __shfl_xor(ss, o); }
    const float mu  = s * (1.f / 768.f);
    const float var = ss * (1.f / 768.f) - mu * mu;
    const float r   = rsqrtf(var + 1e-5f);
#pragma unroll
    for (int j = 0; j < 3; j++) {
      const int c0 = (lane + j * 64) * 4;
      bf16x4 o4;
      o4[0] = (bf16)((v[j].x - mu) * r * lng[c0 + 0] + lnb[c0 + 0]);
      o4[1] = (bf16)((v[j].y - mu) * r * lng[c0 + 1] + lnb[c0 + 1]);
      o4[2] = (bf16)((v[j].z - mu) * r * lng[c0 + 2] + lnb[c0 + 2]);
      o4[3] = (bf16)((v[j].w - mu) * r * lng[c0 + 3] + lnb[c0 + 3]);
      *(bf16x4*)(lnout + (size_t)token * 768 + c0) = o4;
    }
    return;
  }
  __shared__ float tile[32][33];
  const int d = (i >= 6912) ? 1 : 0;
  i -= d * 6912;
  const float* W; bf16* Wt; int K, N, nt;
  if (i < 1728)      { W = d ? qw1 : qw0; Wt = d ? qt1 : qt0; K = 768;  N = 2304; nt = 72; }
  else if (i < 2304) { i -= 1728; W = d ? pw1 : pw0; Wt = d ? pt1 : pt0; K = 768; N = 768; nt = 24; }
  else if (i < 4608) { i -= 2304; W = d ? w11 : w10; Wt = d ? t11 : t10; K = 768; N = 3072; nt = 96; }
  else               { i -= 4608; W = d ? w21 : w20; Wt = d ? t21 : t20; K = 3072; N = 768; nt = 24; }
  const int n0 = (i % nt) * 32, k0 = (i / nt) * 32;
  const int tx = threadIdx.x & 31, ty = threadIdx.x >> 5;
#pragma unroll
  for (int j = ty; j < 32; j += 8)
    tile[j][tx] = W[(size_t)(k0 + j) * N + n0 + tx];
  __syncthreads();
#pragma unroll
  for (int j = ty; j < 32; j += 8)
    Wt[(size_t)(n0 + j) * K + k0 + tx] = (bf16)tile[tx][j];
}

// ---------------- generic GEMM: C[M,N] = A[M,K] @ Bt[N,K]^T ----------------
// MFMA operands swapped (mfma(B,A)): acc reg-axis = N (4 consecutive cols/thread)
// -> vectorized bf16x4 epilogue stores. Math/accumulation order identical.
// EPI 0: bf16 = acc+bias, plus V-transpose side-write for cols>=1536
// EPI 1: bf16 = gelu(acc+bias)
// EPI 4: bf16 partial (split-K over blockIdx.z, no bias), partial stride pstride
// Grid (x*y) must be a multiple of 8 (XCD swizzle bijectivity).
template <int EPI>
__global__ __launch_bounds__(256) void gemm_bt_k(
    const bf16* __restrict__ A, int lda,
    const bf16* __restrict__ Bt, int ldb,
    const float* __restrict__ bias,
    void* __restrict__ outp, int ldc, int K, bf16* __restrict__ vtout,
    size_t pstride) {
  __shared__ __align__(16) bf16 As[128 * 64];
  __shared__ __align__(16) bf16 Bs[128 * 64];
  const int t = threadIdx.x, wave = t >> 6, lane = t & 63;
  // XCD-aware swizzle: dispatch slot -> contiguous work chunk per XCD
  const int nx = gridDim.x;
  const int slot = blockIdx.y * nx + blockIdx.x;
  const int qq = (nx * gridDim.y) >> 3;
  const int work = (slot & 7) * qq + (slot >> 3);
  const int row0 = (work / nx) * 128, col0 = (work % nx) * 128;
  const int wm = wave >> 1, wn = wave & 1;
  const int sr = t >> 3, sc = (t & 7) * 8;
  const int koff = (EPI == 4) ? blockIdx.z * K : 0;

  f32x4 acc[4][4];
#pragma unroll
  for (int m = 0; m < 4; m++)
#pragma unroll
    for (int n = 0; n < 4; n++) acc[m][n] = f32x4{0.f, 0.f, 0.f, 0.f};

  const bf16* a_src = A + (size_t)(row0 + sr) * lda + sc + koff;
  const bf16* b_src = Bt + (size_t)(col0 + sr) * ldb + sc + koff;
  bf16* a_dst = As + wave * 512;
  bf16* b_dst = Bs + wave * 512;

  for (int k0 = 0; k0 < K; k0 += 64) {
#pragma unroll
    for (int i = 0; i < 4; i++) {
      GLOAD16(a_src + (size_t)i * 32 * lda + k0, a_dst + i * 2048);
      GLOAD16(b_src + (size_t)i * 32 * ldb + k0, b_dst + i * 2048);
    }
    __syncthreads();
#pragma unroll
    for (int kk = 0; kk < 2; kk++) {
      const int ko = kk * 32 + (lane >> 4) * 8;
      bf16x8 af[4], bfr[4];
#pragma unroll
      for (int m = 0; m < 4; m++)
        af[m] = *(const bf16x8*)(As + (wm * 64 + m * 16 + (lane & 15)) * 64 + ko);
#pragma unroll
      for (int n = 0; n < 4; n++)
        bfr[n] = *(const bf16x8*)(Bs + (wn * 64 + n * 16 + (lane & 15)) * 64 + ko);
#pragma unroll
      for (int m = 0; m < 4; m++)
#pragma unroll
        for (int n = 0; n < 4; n++)
          acc[m][n] = __builtin_amdgcn_mfma_f32_16x16x32_bf16(bfr[n], af[m], acc[m][n], 0, 0, 0);
    }
    __syncthreads();
  }

  // transposed layout: row = row0+wm*64+m*16+l16, col = col0+wn*64+n*16+g*4+r
  const int rrb = row0 + wm * 64 + (lane & 15);
  const int cbb = col0 + wn * 64 + ((lane >> 4) << 2);
  bf16* outb = nullptr;
  if constexpr (EPI == 4)
    outb = (bf16*)outp + (size_t)blockIdx.z * pstride;
#pragma unroll
  for (int m = 0; m < 4; m++) {
    const int row = rrb + m * 16;
#pragma unroll
    for (int n = 0; n < 4; n++) {
      const int c0 = cbb + n * 16;
      f32x4 v;
      if constexpr (EPI == 4) {
        v[0] = acc[m][n][0]; v[1] = acc[m][n][1];
        v[2] = acc[m][n][2]; v[3] = acc[m][n][3];
      } else {
        const float4 b4 = *(const float4*)(bias + c0);
        v[0] = acc[m][n][0] + b4.x; v[1] = acc[m][n][1] + b4.y;
        v[2] = acc[m][n][2] + b4.z; v[3] = acc[m][n][3] + b4.w;
      }
      if constexpr (EPI == 1) {
        v[0] = gelu_f(v[0]); v[1] = gelu_f(v[1]);
        v[2] = gelu_f(v[2]); v[3] = gelu_f(v[3]);
      }
      bf16x4 o4;
      o4[0] = (bf16)v[0]; o4[1] = (bf16)v[1]; o4[2] = (bf16)v[2]; o4[3] = (bf16)v[3];
      if constexpr (EPI == 4) {
        *(bf16x4*)(outb + (size_t)row * ldc + c0) = o4;
      } else {
        *(bf16x4*)((bf16*)outp + (size_t)row * ldc + c0) = o4;
      }
      if constexpr (EPI == 0) {
        // fused V-transpose: cols >= 1536 are V; write vT[bh][d][q]
        if (c0 >= 1536) {
          const int bq = row >> 10, q = row & 1023;
          const int hd = c0 - 1536, h = hd >> 6, dd = hd & 63;
          bf16* vb = vtout + (size_t)(bq * 12 + h) * 65536 + (size_t)dd * 1024 + q;
          vb[0] = o4[0]; vb[1024] = o4[1]; vb[2048] = o4[2]; vb[3072] = o4[3];
        }
      }
    }
  }
}

// ------ split-K reduce + optional fused LayerNorm of the result ------
// MODE 0: o = sum(partials) + bias + res
// MODE 1: o = 0.5*(sum + bias + res + res2)
// writes xout (f32); if LN: also writes LN(o)*g+b as bf16 to lnout.
// NOTE: lnout may alias partial 0 (each thread reads only its own elements
// before writing them; no cross-thread access to partials).
template <int NP, int MODE, bool LN>
__global__ __launch_bounds__(256) void reduce_ln_k(
    const bf16* __restrict__ pbuf, const float* __restrict__ bias,
    const float* __restrict__ res, const float* __restrict__ res2,
    float* __restrict__ xout, const float* __restrict__ g,
    const float* __restrict__ b, bf16* __restrict__ lnout) {
  const int token = blockIdx.x * 4 + (threadIdx.x >> 6);
  const int lane  = threadIdx.x & 63;
  float o[12];
  float s = 0.f, ss = 0.f;
#pragma unroll
  for (int j = 0; j < 3; j++) {
    const int c0 = (lane + j * 64) * 4;
    const size_t idx = (size_t)token * 768 + c0;
    const float4 b4 = *(const float4*)(bias + c0);
    float a0 = b4.x, a1 = b4.y, a2 = b4.z, a3 = b4.w;
#pragma unroll
    for (int sp = 0; sp < NP; sp++) {
      const bf16x4 pp = *(const bf16x4*)(pbuf + (size_t)sp * 3145728 + idx);
      a0 += (float)pp[0]; a1 += (float)pp[1]; a2 += (float)pp[2]; a3 += (float)pp[3];
    }
    const float4 r4 = *(const float4*)(res + idx);
    float4 ov;
    if constexpr (MODE == 0) {
      ov.x = a0 + r4.x; ov.y = a1 + r4.y; ov.z = a2 + r4.z; ov.w = a3 + r4.w;
    } else {
      const float4 r2 = *(const float4*)(res2 + idx);
      ov.x = 0.5f * (a0 + r4.x + r2.x); ov.y = 0.5f * (a1 + r4.y + r2.y);
      ov.z = 0.5f * (a2 + r4.z + r2.z); ov.w = 0.5f * (a3 + r4.w + r2.w);
    }
    *(float4*)(xout + idx) = ov;
    o[j * 4 + 0] = ov.x; o[j * 4 + 1] = ov.y; o[j * 4 + 2] = ov.z; o[j * 4 + 3] = ov.w;
    s  += ov.x + ov.y + ov.z + ov.w;
    ss += ov.x * ov.x + ov.y * ov.y + ov.z * ov.z + ov.w * ov.w;
  }
  if constexpr (LN) {
#pragma unroll
    for (int off = 32; off > 0; off >>= 1) { s += __shfl_xor(s, off); ss += __shfl_xor(ss, off); }
    const float mu  = s * (1.f / 768.f);
    const float var = ss * (1.f / 768.f) - mu * mu;
    const float r   = rsqrtf(var + 1e-5f);
#pragma unroll
    for (int j = 0; j < 3; j++) {
      const int c0 = (lane + j * 64) * 4;
      bf16x4 o4;
      o4[0] = (bf16)((o[j * 4 + 0] - mu) * r * g[c0 + 0] + b[c0 + 0]);
      o4[1] = (bf16)((o[j * 4 + 1] - mu) * r * g[c0 + 1] + b[c0 + 1]);
      o4[2] = (bf16)((o[j * 4 + 2] - mu) * r * g[c0 + 2] + b[c0 + 2]);
      o4[3] = (bf16)((o[j * 4 + 3] - mu) * r * g[c0 + 3] + b[c0 + 3]);
      *(bf16x4*)(lnout + (size_t)token * 768 + c0) = o4;
    }
  }
}

// ---------------- fused attention: S^T via mfma(K,Q), 2-pass softmax (no max), PV ----
__global__ __launch_bounds__(256) void fattn_k(const bf16* __restrict__ qkv,
                                               const bf16* __restrict__ vT,
                                               float* __restrict__ attn,
                                               bf16* __restrict__ aout) {
  __shared__ __align__(16) bf16 Ks[128 * 64];     // K tile, source-swizzled
  __shared__ __align__(16) bf16 Ps[4 * 16 * 128]; // per-wave P tile, swizzled

  const float S2 = 0.18033688011112042f;  // 0.125 * log2(e)

  const int bid = blockIdx.x;
  const int xcd = bid & 7, within = bid >> 3;
  const int bh = xcd * 6 + (within >> 4);
  const int qb = within & 15;
  const int b = bh / 12, h = bh % 12;

  const int t = threadIdx.x, w = t >> 6, lane = t & 63;
  const int g = lane >> 4, l16 = lane & 15;
  const int q0 = qb * 64;

  const bf16* qbp = qkv + (size_t)b * 1024 * 2304 + h * 64;
  const bf16* kbp = qbp + 768;
  const bf16* vt = vT + (size_t)bh * 65536;
  float* Pout = attn + (size_t)bh * 1048576;
  bf16* Pw = Ps + w * 2048;

  bf16x8 qf[2];
#pragma unroll
  for (int kk = 0; kk < 2; kk++)
    qf[kk] = *(const bf16x8*)(qbp + (size_t)(q0 + w * 16 + l16) * 2304 + kk * 32 + g * 8);

  const int kvr = t >> 3, sl = t & 7;

  float l_run = 0.f;

  // ---------------- pass 1: row sum of exp2(S*S2) (max-free: |S*scale| is small) ----
  for (int kv0 = 0; kv0 < 1024; kv0 += 128) {
#pragma unroll
    for (int i = 0; i < 4; i++) {
      const int kvl = i * 32 + kvr;
      GLOAD16(kbp + (size_t)(kv0 + kvl) * 2304 + (sl ^ (kvl & 7)) * 8,
              Ks + i * 2048 + t * 8);
    }
    __syncthreads();
    f32x4 st[8];
#pragma unroll
    for (int mk = 0; mk < 8; mk++) st[mk] = f32x4{0.f, 0.f, 0.f, 0.f};
    __builtin_amdgcn_s_setprio(1);
#pragma unroll
    for (int kk = 0; kk < 2; kk++) {
#pragma unroll
      for (int mk = 0; mk < 8; mk++) {
        const int kv = mk * 16 + l16;
        const bf16x8 kf = *(const bf16x8*)(Ks + ((kv * 64 + kk * 32 + g * 8) ^ ((kv & 7) << 3)));
        st[mk] = __builtin_amdgcn_mfma_f32_16x16x32_bf16(kf, qf[kk], st[mk], 0, 0, 0);
      }
    }
    __builtin_amdgcn_s_setprio(0);
    __syncthreads();
    float sum = 0.f;
#pragma unroll
    for (int mk = 0; mk < 8; mk++)
#pragma unroll
      for (int r = 0; r < 4; r++) sum += exp2f(st[mk][r] * S2);
    sum += __shfl_xor(sum, 16);
    sum += __shfl_xor(sum, 32);
    l_run += sum;
  }

  const float invl = 1.f / l_run;

  f32x4 oacc[4];
#pragma unroll
  for (int nd = 0; nd < 4; nd++) oacc[nd] = f32x4{0.f, 0.f, 0.f, 0.f};

  // ---------------- pass 2: recompute S, write P, PV ----------------
  for (int kv0 = 0; kv0 < 1024; kv0 += 128) {
#pragma unroll
    for (int i = 0; i < 4; i++) {
      const int kvl = i * 32 + kvr;
      GLOAD16(kbp + (size_t)(kv0 + kvl) * 2304 + (sl ^ (kvl & 7)) * 8,
              Ks + i * 2048 + t * 8);
    }
    __syncthreads();
    f32x4 st[8];
#pragma unroll
    for (int mk = 0; mk < 8; mk++) st[mk] = f32x4{0.f, 0.f, 0.f, 0.f};
    __builtin_amdgcn_s_setprio(1);
#pragma unroll
    for (int kk = 0; kk < 2; kk++) {
#pragma unroll
      for (int mk = 0; mk < 8; mk++) {
        const int kv = mk * 16 + l16;
        const bf16x8 kf = *(const bf16x8*)(Ks + ((kv * 64 + kk * 32 + g * 8) ^ ((kv & 7) << 3)));
        st[mk] = __builtin_amdgcn_mfma_f32_16x16x32_bf16(kf, qf[kk], st[mk], 0, 0, 0);
      }
    }
    __builtin_amdgcn_s_setprio(0);
    __syncthreads();

    const int q = q0 + w * 16 + l16;
#pragma unroll
    for (int mk = 0; mk < 8; mk++) {
      f32x4 pv;
      pv[0] = exp2f(st[mk][0] * S2) * invl;
      pv[1] = exp2f(st[mk][1] * S2) * invl;
      pv[2] = exp2f(st[mk][2] * S2) * invl;
      pv[3] = exp2f(st[mk][3] * S2) * invl;
      __builtin_nontemporal_store(pv, (f32x4*)(Pout + (size_t)q * 1024 + kv0 + mk * 16 + g * 4));
      bf16x4 pb;
      pb[0] = (bf16)pv[0]; pb[1] = (bf16)pv[1]; pb[2] = (bf16)pv[2]; pb[3] = (bf16)pv[3];
      *(bf16x4*)(Pw + ((l16 * 128 + mk * 16 + g * 4) ^ ((l16 & 7) << 3))) = pb;
    }

#pragma unroll
    for (int kkv = 0; kkv < 4; kkv++) {
      const bf16x8 pf = *(const bf16x8*)(Pw + ((l16 * 128 + kkv * 32 + g * 8) ^ ((l16 & 7) << 3)));
      bf16x8 vf[4];
#pragma unroll
      for (int nd = 0; nd < 4; nd++)
        vf[nd] = *(const bf16x8*)(vt + (size_t)(nd * 16 + l16) * 1024 + kv0 + kkv * 32 + g * 8);
      __builtin_amdgcn_s_setprio(1);
#pragma unroll
      for (int nd = 0; nd < 4; nd++)
        oacc[nd] = __builtin_amdgcn_mfma_f32_16x16x32_bf16(vf[nd], pf, oacc[nd], 0, 0, 0);
      __builtin_amdgcn_s_setprio(0);
    }
  }

  // swapped PV layout: q = l16 axis, d = reg axis -> vectorized bf16x4 stores
  {
    const int q = q0 + w * 16 + l16;
    bf16* ob = aout + (size_t)(b * 1024 + q) * 768 + h * 64 + g * 4;
#pragma unroll
    for (int nd = 0; nd < 4; nd++) {
      bf16x4 o4;
      o4[0] = (bf16)oacc[nd][0]; o4[1] = (bf16)oacc[nd][1];
      o4[2] = (bf16)oacc[nd][2]; o4[3] = (bf16)oacc[nd][3];
      *(bf16x4*)(ob + nd * 16) = o4;
    }
  }
}

// ---------------- host ----------------
extern "C" void kernel_launch(void* const* d_in, const int* in_sizes, int n_in,
                              void* d_out, int out_size, void* d_ws, size_t ws_size,
                              hipStream_t stream) {
  (void)in_sizes; (void)n_in; (void)out_size; (void)ws_size;
  const float* x = (const float*)d_in[0];
#define IN(d, i) ((const float*)d_in[1 + (d) * 12 + (i)])
  float* outF = (float*)d_out;
  float* attnp[2] = {outF + 3145728, outF + 3145728 + 50331648};

  char* p = (char*)d_ws;
  auto alloc = [&](size_t bytes) { void* r = p; p += bytes; return r; };
  bf16 *qkv_wt[2], *proj_wt[2], *w1t[2], *w2t[2];
  for (int d = 0; d < 2; d++) {
    qkv_wt[d]  = (bf16*)alloc((size_t)2304 * 768 * 2);
    proj_wt[d] = (bf16*)alloc((size_t)768 * 768 * 2);
    w1t[d]     = (bf16*)alloc((size_t)3072 * 768 * 2);
    w2t[d]     = (bf16*)alloc((size_t)768 * 3072 * 2);
  }
  // hbuf+qkvb form one contiguous 25.17 MB region; reused as up to 4 bf16
  // split-K partials (4 x 3145728 elems) while both buffers are dead.
  bf16*  hbuf = (bf16*)alloc((size_t)4096 * 768 * 2);
  bf16*  qkvb = (bf16*)alloc((size_t)4096 * 2304 * 2);
  bf16*  pbuf = hbuf;
  bf16*  vT   = (bf16*)alloc((size_t)48 * 64 * 1024 * 2);
  bf16*  aout = (bf16*)alloc((size_t)4096 * 768 * 2);
  bf16*  hid  = (bf16*)alloc((size_t)4096 * 3072 * 2);
  float* xa   = (float*)alloc((size_t)4096 * 768 * 4);
  float* xb   = (float*)alloc((size_t)4096 * 768 * 4);

  // weights transpose (13824 blocks) + ln0 (1024 blocks) in one dispatch
  transpose_all_k<<<14848, 256, 0, stream>>>(
      IN(0, 0), qkv_wt[0], IN(0, 2), proj_wt[0], IN(0, 8), w1t[0], IN(0, 10), w2t[0],
      IN(1, 0), qkv_wt[1], IN(1, 2), proj_wt[1], IN(1, 8), w1t[1], IN(1, 10), w2t[1],
      x, IN(0, 4), IN(0, 5), hbuf);

  // ---- layer 0 attention: xa = x + attn0(hbuf); also LN1_1(xa) -> hbuf ----
  gemm_bt_k<0><<<dim3(18, 32), 256, 0, stream>>>(hbuf, 768, qkv_wt[0], 768, IN(0, 1),
                                                 qkvb, 2304, 768, vT, 0);
  fattn_k<<<768, 256, 0, stream>>>(qkvb, vT, attnp[0], aout);
  gemm_bt_k<4><<<dim3(6, 32, 2), 256, 0, stream>>>(aout, 768, proj_wt[0], 768, nullptr,
                                                   pbuf, 768, 384, nullptr, 3145728);
  reduce_ln_k<2, 0, true><<<1024, 256, 0, stream>>>(pbuf, IN(0, 3), x, nullptr,
                                                    xa, IN(1, 4), IN(1, 5), hbuf);
  // ---- layer 1 attention: xb = xa + attn1(hbuf); also LN2_1(xb) -> hbuf ----
  gemm_bt_k<0><<<dim3(18, 32), 256, 0, stream>>>(hbuf, 768, qkv_wt[1], 768, IN(1, 1),
                                                 qkvb, 2304, 768, vT, 0);
  fattn_k<<<768, 256, 0, stream>>>(qkvb, vT, attnp[1], aout);
  gemm_bt_k<4><<<dim3(6, 32, 2), 256, 0, stream>>>(aout, 768, proj_wt[1], 768, nullptr,
                                                   pbuf, 768, 384, nullptr, 3145728);
  reduce_ln_k<2, 0, true><<<1024, 256, 0, stream>>>(pbuf, IN(1, 3), xa, nullptr,
                                                    xb, IN(1, 6), IN(1, 7), hbuf);
  // ---- layer 1 MLP + blend: xa = 0.5*(xa + xb + mlp1(hbuf)); LN2_0(xa) -> hbuf ----
  gemm_bt_k<1><<<dim3(24, 32), 256, 0, stream>>>(hbuf, 768, w1t[1], 768, IN(1, 9),
                                                 hid, 3072, 768, nullptr, 0);
  gemm_bt_k<4><<<dim3(6, 32, 4), 256, 0, stream>>>(hid, 3072, w2t[1], 3072, nullptr,
                                                   pbuf, 768, 768, nullptr, 3145728);
  reduce_ln_k<4, 1, true><<<1024, 256, 0, stream>>>(pbuf, IN(1, 11), xb, xa,
                                                    xa, IN(0, 6), IN(0, 7), hbuf);
  // ---- layer 0 MLP: out = xa + mlp0(hbuf) ----
  gemm_bt_k<1><<<dim3(24, 32), 256, 0, stream>>>(hbuf, 768, w1t[0], 768, IN(0, 9),
                                                 hid, 3072, 768, nullptr, 0);
  gemm_bt_k<4><<<dim3(6, 32, 4), 256, 0, stream>>>(hid, 3072, w2t[0], 3072, nullptr,
                                                   pbuf, 768, 768, nullptr, 3145728);
  reduce_ln_k<4, 0, false><<<1024, 256, 0, stream>>>(pbuf, IN(0, 11), xa, nullptr,
                                                     outF, nullptr, nullptr, nullptr);
#undef IN
}

// Round 10
// 477.082 us; speedup vs baseline: 1.1077x; 1.1077x over previous
//
#include <hip/hip_runtime.h>
#include <hip/hip_bf16.h>
#include <stdint.h>

typedef __bf16 bf16;
typedef __bf16 bf16x8 __attribute__((ext_vector_type(8)));
typedef __bf16 bf16x4 __attribute__((ext_vector_type(4)));
typedef float  f32x4  __attribute__((ext_vector_type(4)));

#define GLOAD16(gsrc, ldst)                                                        \
  __builtin_amdgcn_global_load_lds(                                               \
      (const __attribute__((address_space(1))) void*)(gsrc),                      \
      (__attribute__((address_space(3))) void*)(ldst), 16, 0, 0)

__device__ __forceinline__ float gelu_f(float v) {
  return 0.5f * v * (1.0f + erff(v * 0.70710678118654752f));
}

// ---- batched transpose+cast for all 8 weights  +  fused ln0 (blocks >= 13824) ----
__global__ __launch_bounds__(256) void transpose_all_k(
    const float* __restrict__ qw0, bf16* __restrict__ qt0,
    const float* __restrict__ pw0, bf16* __restrict__ pt0,
    const float* __restrict__ w10, bf16* __restrict__ t10,
    const float* __restrict__ w20, bf16* __restrict__ t20,
    const float* __restrict__ qw1, bf16* __restrict__ qt1,
    const float* __restrict__ pw1, bf16* __restrict__ pt1,
    const float* __restrict__ w11, bf16* __restrict__ t11,
    const float* __restrict__ w21, bf16* __restrict__ t21,
    const float* __restrict__ x, const float* __restrict__ lng,
    const float* __restrict__ lnb, bf16* __restrict__ lnout) {
  int i = blockIdx.x;
  if (i >= 13824) {
    const int token = (i - 13824) * 4 + (threadIdx.x >> 6);
    const int lane  = threadIdx.x & 63;
    const float4* xp = (const float4*)(x + (size_t)token * 768);
    float4 v[3];
    float s = 0.f, ss = 0.f;
#pragma unroll
    for (int j = 0; j < 3; j++) {
      v[j] = xp[lane + j * 64];
      s  += v[j].x + v[j].y + v[j].z + v[j].w;
      ss += v[j].x * v[j].x + v[j].y * v[j].y + v[j].z * v[j].z + v[j].w * v[j].w;
    }
#pragma unroll
    for (int o = 32; o > 0; o >>= 1) { s += __shfl_xor(s, o); ss += __shfl_xor(ss, o); }
    const float mu  = s * (1.f / 768.f);
    const float var = ss * (1.f / 768.f) - mu * mu;
    const float r   = rsqrtf(var + 1e-5f);
#pragma unroll
    for (int j = 0; j < 3; j++) {
      const int c0 = (lane + j * 64) * 4;
      bf16x4 o4;
      o4[0] = (bf16)((v[j].x - mu) * r * lng[c0 + 0] + lnb[c0 + 0]);
      o4[1] = (bf16)((v[j].y - mu) * r * lng[c0 + 1] + lnb[c0 + 1]);
      o4[2] = (bf16)((v[j].z - mu) * r * lng[c0 + 2] + lnb[c0 + 2]);
      o4[3] = (bf16)((v[j].w - mu) * r * lng[c0 + 3] + lnb[c0 + 3]);
      *(bf16x4*)(lnout + (size_t)token * 768 + c0) = o4;
    }
    return;
  }
  __shared__ float tile[32][33];
  const int d = (i >= 6912) ? 1 : 0;
  i -= d * 6912;
  const float* W; bf16* Wt; int K, N, nt;
  if (i < 1728)      { W = d ? qw1 : qw0; Wt = d ? qt1 : qt0; K = 768;  N = 2304; nt = 72; }
  else if (i < 2304) { i -= 1728; W = d ? pw1 : pw0; Wt = d ? pt1 : pt0; K = 768; N = 768; nt = 24; }
  else if (i < 4608) { i -= 2304; W = d ? w11 : w10; Wt = d ? t11 : t10; K = 768; N = 3072; nt = 96; }
  else               { i -= 4608; W = d ? w21 : w20; Wt = d ? t21 : t20; K = 3072; N = 768; nt = 24; }
  const int n0 = (i % nt) * 32, k0 = (i / nt) * 32;
  const int tx = threadIdx.x & 31, ty = threadIdx.x >> 5;
#pragma unroll
  for (int j = ty; j < 32; j += 8)
    tile[j][tx] = W[(size_t)(k0 + j) * N + n0 + tx];
  __syncthreads();
#pragma unroll
  for (int j = ty; j < 32; j += 8)
    Wt[(size_t)(n0 + j) * K + k0 + tx] = (bf16)tile[tx][j];
}

// ============ 256x256-tile 8-wave deep-pipelined GEMM: C = A[M,K] @ Bt[N,K]^T ====
// 8 waves (2M x 4N), per-wave output 128x64, BK=64, double-buffered 128 KiB LDS,
// XOR-swizzled (16B slot ^ row&7, pre-swizzled gload source + swizzled ds_read).
// Pipeline: group j reads buf[j&1] while staging K-tile j+1 into the other
// buffer (freed at the previous __syncthreads). One __syncthreads per K-tile
// is both the vmcnt(0) visibility gate and the overwrite gate (race-free).
// EPI 0: bf16 = acc+bias, plus V-transpose side-write for cols>=1536
// EPI 1: bf16 = gelu(acc+bias)
// EPI 4: bf16 partial (split-K over blockIdx.z, no bias), stride pstride
template <int EPI>
__global__ __launch_bounds__(512, 2) void gemm256_k(
    const bf16* __restrict__ A, int lda,
    const bf16* __restrict__ Bt, int ldb,
    const float* __restrict__ bias,
    void* __restrict__ outp, int ldc, int K, bf16* __restrict__ vtout,
    size_t pstride) {
  extern __shared__ __align__(16) bf16 smem[];
  // As[tb][hh][128][64], Bs likewise; 32768 elements each
  bf16* As = smem;
  bf16* Bs = smem + 32768;

  const int t = threadIdx.x, wave = t >> 6, lane = t & 63;
  const int g = lane >> 4, l16 = lane & 15;
  const int wm = wave >> 2, wn = wave & 3;
  const int row0 = blockIdx.y * 256, col0 = blockIdx.x * 256;
  const int koff = (EPI == 4) ? blockIdx.z * K : 0;
  const int KT = K >> 6;

  f32x4 acc[8][4];
#pragma unroll
  for (int m = 0; m < 8; m++)
#pragma unroll
    for (int n = 0; n < 4; n++) acc[m][n] = f32x4{0.f, 0.f, 0.f, 0.f};

  // staging: 512 threads x (2 halves x 2 loads) = 8 gload_lds -> one K-tile (A+B)
  const int s_lr0 = t >> 3, s_sl = t & 7;

  auto stage = [&](int kt, int tb) {
    const int k0 = koff + (kt << 6);
#pragma unroll
    for (int hh = 0; hh < 2; ++hh) {
#pragma unroll
      for (int l = 0; l < 2; ++l) {
        const int lr = s_lr0 + l * 64;             // 0..127 within half
        const int swz = (s_sl ^ (lr & 7)) << 3;    // pre-swizzled source column
        const int dst = ((tb * 2 + hh) * 128 + lr) * 64 + (s_sl << 3);
        GLOAD16(A + (size_t)(row0 + hh * 128 + lr) * lda + k0 + swz, As + dst);
        GLOAD16(Bt + (size_t)(col0 + hh * 128 + lr) * ldb + k0 + swz, Bs + dst);
      }
    }
  };

  const int hb = wn >> 1;                 // wave's B half
  const int bRow = (wn & 1) << 6;         // B row base within half

  stage(0, 0);
  __syncthreads();

  for (int j = 0; j < KT; ++j) {
    const int p = j & 1;
    if (j + 1 < KT) stage(j + 1, p ^ 1);

    // B fragments for this K-tile (kept in regs across the 4 phases)
    bf16x8 bfr[4][2];
#pragma unroll
    for (int n = 0; n < 4; ++n)
#pragma unroll
      for (int kk = 0; kk < 2; ++kk) {
        const int r = bRow + n * 16 + l16;
        bfr[n][kk] = *(const bf16x8*)(Bs + ((p * 2 + hb) * 128 + r) * 64 +
                                      ((((kk << 2) + g) ^ (r & 7)) << 3));
      }
    // 4 quadrant phases (2 m-frags x 4 n x 2 kk = 16 MFMA each)
#pragma unroll
    for (int quad = 0; quad < 4; ++quad) {
      bf16x8 af[2][2];
#pragma unroll
      for (int mm = 0; mm < 2; ++mm)
#pragma unroll
        for (int kk = 0; kk < 2; ++kk) {
          const int r = (quad * 2 + mm) * 16 + l16;
          af[mm][kk] = *(const bf16x8*)(As + ((p * 2 + wm) * 128 + r) * 64 +
                                        ((((kk << 2) + g) ^ (r & 7)) << 3));
        }
      __builtin_amdgcn_s_barrier();
      __builtin_amdgcn_s_setprio(1);
#pragma unroll
      for (int mm = 0; mm < 2; ++mm)
#pragma unroll
        for (int n = 0; n < 4; ++n)
#pragma unroll
          for (int kk = 0; kk < 2; ++kk)
            acc[quad * 2 + mm][n] = __builtin_amdgcn_mfma_f32_16x16x32_bf16(
                bfr[n][kk], af[mm][kk], acc[quad * 2 + mm][n], 0, 0, 0);
      __builtin_amdgcn_s_setprio(0);
    }
    __syncthreads();   // gate: vmcnt(0)+lgkmcnt(0)+barrier (visibility + overwrite)
  }

  // epilogue: row = row0 + wm*128 + m*16 + l16 ; col = col0 + wn*64 + n*16 + g*4 + r
  const int rowb = row0 + wm * 128 + l16;
  const int colb = col0 + wn * 64 + (g << 2);
  bf16* outb = (bf16*)outp;
  if constexpr (EPI == 4) outb += (size_t)blockIdx.z * pstride;
#pragma unroll
  for (int m = 0; m < 8; ++m) {
    const int row = rowb + m * 16;
#pragma unroll
    for (int n = 0; n < 4; ++n) {
      const int c0 = colb + n * 16;
      f32x4 v = acc[m][n];
      if constexpr (EPI != 4) {
        const float4 b4 = *(const float4*)(bias + c0);
        v[0] += b4.x; v[1] += b4.y; v[2] += b4.z; v[3] += b4.w;
      }
      if constexpr (EPI == 1) {
        v[0] = gelu_f(v[0]); v[1] = gelu_f(v[1]);
        v[2] = gelu_f(v[2]); v[3] = gelu_f(v[3]);
      }
      bf16x4 o4;
      o4[0] = (bf16)v[0]; o4[1] = (bf16)v[1]; o4[2] = (bf16)v[2]; o4[3] = (bf16)v[3];
      *(bf16x4*)(outb + (size_t)row * ldc + c0) = o4;
      if constexpr (EPI == 0) {
        if (c0 >= 1536) {   // fused V-transpose side-write
          const int bq = row >> 10, q = row & 1023;
          const int hd = c0 - 1536, h = hd >> 6, dd = hd & 63;
          bf16* vb = vtout + (size_t)(bq * 12 + h) * 65536 + (size_t)dd * 1024 + q;
          vb[0] = o4[0]; vb[1024] = o4[1]; vb[2048] = o4[2]; vb[3072] = o4[3];
        }
      }
    }
  }
}

// ------ split-K reduce + optional fused LayerNorm of the result ------
template <int NP, int MODE, bool LN>
__global__ __launch_bounds__(256) void reduce_ln_k(
    const bf16* __restrict__ pbuf, const float* __restrict__ bias,
    const float* __restrict__ res, const float* __restrict__ res2,
    float* __restrict__ xout, const float* __restrict__ g,
    const float* __restrict__ b, bf16* __restrict__ lnout) {
  const int token = blockIdx.x * 4 + (threadIdx.x >> 6);
  const int lane  = threadIdx.x & 63;
  float o[12];
  float s = 0.f, ss = 0.f;
#pragma unroll
  for (int j = 0; j < 3; j++) {
    const int c0 = (lane + j * 64) * 4;
    const size_t idx = (size_t)token * 768 + c0;
    const float4 b4 = *(const float4*)(bias + c0);
    float a0 = b4.x, a1 = b4.y, a2 = b4.z, a3 = b4.w;
#pragma unroll
    for (int sp = 0; sp < NP; sp++) {
      const bf16x4 pp = *(const bf16x4*)(pbuf + (size_t)sp * 3145728 + idx);
      a0 += (float)pp[0]; a1 += (float)pp[1]; a2 += (float)pp[2]; a3 += (float)pp[3];
    }
    const float4 r4 = *(const float4*)(res + idx);
    float4 ov;
    if constexpr (MODE == 0) {
      ov.x = a0 + r4.x; ov.y = a1 + r4.y; ov.z = a2 + r4.z; ov.w = a3 + r4.w;
    } else {
      const float4 r2 = *(const float4*)(res2 + idx);
      ov.x = 0.5f * (a0 + r4.x + r2.x); ov.y = 0.5f * (a1 + r4.y + r2.y);
      ov.z = 0.5f * (a2 + r4.z + r2.z); ov.w = 0.5f * (a3 + r4.w + r2.w);
    }
    *(float4*)(xout + idx) = ov;
    o[j * 4 + 0] = ov.x; o[j * 4 + 1] = ov.y; o[j * 4 + 2] = ov.z; o[j * 4 + 3] = ov.w;
    s  += ov.x + ov.y + ov.z + ov.w;
    ss += ov.x * ov.x + ov.y * ov.y + ov.z * ov.z + ov.w * ov.w;
  }
  if constexpr (LN) {
#pragma unroll
    for (int off = 32; off > 0; off >>= 1) { s += __shfl_xor(s, off); ss += __shfl_xor(ss, off); }
    const float mu  = s * (1.f / 768.f);
    const float var = ss * (1.f / 768.f) - mu * mu;
    const float r   = rsqrtf(var + 1e-5f);
#pragma unroll
    for (int j = 0; j < 3; j++) {
      const int c0 = (lane + j * 64) * 4;
      bf16x4 o4;
      o4[0] = (bf16)((o[j * 4 + 0] - mu) * r * g[c0 + 0] + b[c0 + 0]);
      o4[1] = (bf16)((o[j * 4 + 1] - mu) * r * g[c0 + 1] + b[c0 + 1]);
      o4[2] = (bf16)((o[j * 4 + 2] - mu) * r * g[c0 + 2] + b[c0 + 2]);
      o4[3] = (bf16)((o[j * 4 + 3] - mu) * r * g[c0 + 3] + b[c0 + 3]);
      *(bf16x4*)(lnout + (size_t)token * 768 + c0) = o4;
    }
  }
}

// ---------------- fused attention: S^T via mfma(K,Q), 2-pass softmax (no max), PV ----
__global__ __launch_bounds__(256) void fattn_k(const bf16* __restrict__ qkv,
                                               const bf16* __restrict__ vT,
                                               float* __restrict__ attn,
                                               bf16* __restrict__ aout) {
  __shared__ __align__(16) bf16 Ks[128 * 64];
  __shared__ __align__(16) bf16 Ps[4 * 16 * 128];

  const float S2 = 0.18033688011112042f;  // 0.125 * log2(e)

  const int bid = blockIdx.x;
  const int xcd = bid & 7, within = bid >> 3;
  const int bh = xcd * 6 + (within >> 4);
  const int qb = within & 15;
  const int b = bh / 12, h = bh % 12;

  const int t = threadIdx.x, w = t >> 6, lane = t & 63;
  const int g = lane >> 4, l16 = lane & 15;
  const int q0 = qb * 64;

  const bf16* qbp = qkv + (size_t)b * 1024 * 2304 + h * 64;
  const bf16* kbp = qbp + 768;
  const bf16* vt = vT + (size_t)bh * 65536;
  float* Pout = attn + (size_t)bh * 1048576;
  bf16* Pw = Ps + w * 2048;

  bf16x8 qf[2];
#pragma unroll
  for (int kk = 0; kk < 2; kk++)
    qf[kk] = *(const bf16x8*)(qbp + (size_t)(q0 + w * 16 + l16) * 2304 + kk * 32 + g * 8);

  const int kvr = t >> 3, sl = t & 7;

  float l_run = 0.f;

  for (int kv0 = 0; kv0 < 1024; kv0 += 128) {
#pragma unroll
    for (int i = 0; i < 4; i++) {
      const int kvl = i * 32 + kvr;
      GLOAD16(kbp + (size_t)(kv0 + kvl) * 2304 + (sl ^ (kvl & 7)) * 8,
              Ks + i * 2048 + t * 8);
    }
    __syncthreads();
    f32x4 st[8];
#pragma unroll
    for (int mk = 0; mk < 8; mk++) st[mk] = f32x4{0.f, 0.f, 0.f, 0.f};
    __builtin_amdgcn_s_setprio(1);
#pragma unroll
    for (int kk = 0; kk < 2; kk++) {
#pragma unroll
      for (int mk = 0; mk < 8; mk++) {
        const int kv = mk * 16 + l16;
        const bf16x8 kf = *(const bf16x8*)(Ks + ((kv * 64 + kk * 32 + g * 8) ^ ((kv & 7) << 3)));
        st[mk] = __builtin_amdgcn_mfma_f32_16x16x32_bf16(kf, qf[kk], st[mk], 0, 0, 0);
      }
    }
    __builtin_amdgcn_s_setprio(0);
    __syncthreads();
    float sum = 0.f;
#pragma unroll
    for (int mk = 0; mk < 8; mk++)
#pragma unroll
      for (int r = 0; r < 4; r++) sum += exp2f(st[mk][r] * S2);
    sum += __shfl_xor(sum, 16);
    sum += __shfl_xor(sum, 32);
    l_run += sum;
  }

  const float invl = 1.f / l_run;

  f32x4 oacc[4];
#pragma unroll
  for (int nd = 0; nd < 4; nd++) oacc[nd] = f32x4{0.f, 0.f, 0.f, 0.f};

  for (int kv0 = 0; kv0 < 1024; kv0 += 128) {
#pragma unroll
    for (int i = 0; i < 4; i++) {
      const int kvl = i * 32 + kvr;
      GLOAD16(kbp + (size_t)(kv0 + kvl) * 2304 + (sl ^ (kvl & 7)) * 8,
              Ks + i * 2048 + t * 8);
    }
    __syncthreads();
    f32x4 st[8];
#pragma unroll
    for (int mk = 0; mk < 8; mk++) st[mk] = f32x4{0.f, 0.f, 0.f, 0.f};
    __builtin_amdgcn_s_setprio(1);
#pragma unroll
    for (int kk = 0; kk < 2; kk++) {
#pragma unroll
      for (int mk = 0; mk < 8; mk++) {
        const int kv = mk * 16 + l16;
        const bf16x8 kf = *(const bf16x8*)(Ks + ((kv * 64 + kk * 32 + g * 8) ^ ((kv & 7) << 3)));
        st[mk] = __builtin_amdgcn_mfma_f32_16x16x32_bf16(kf, qf[kk], st[mk], 0, 0, 0);
      }
    }
    __builtin_amdgcn_s_setprio(0);
    __syncthreads();

    const int q = q0 + w * 16 + l16;
#pragma unroll
    for (int mk = 0; mk < 8; mk++) {
      f32x4 pv;
      pv[0] = exp2f(st[mk][0] * S2) * invl;
      pv[1] = exp2f(st[mk][1] * S2) * invl;
      pv[2] = exp2f(st[mk][2] * S2) * invl;
      pv[3] = exp2f(st[mk][3] * S2) * invl;
      __builtin_nontemporal_store(pv, (f32x4*)(Pout + (size_t)q * 1024 + kv0 + mk * 16 + g * 4));
      bf16x4 pb;
      pb[0] = (bf16)pv[0]; pb[1] = (bf16)pv[1]; pb[2] = (bf16)pv[2]; pb[3] = (bf16)pv[3];
      *(bf16x4*)(Pw + ((l16 * 128 + mk * 16 + g * 4) ^ ((l16 & 7) << 3))) = pb;
    }

#pragma unroll
    for (int kkv = 0; kkv < 4; kkv++) {
      const bf16x8 pf = *(const bf16x8*)(Pw + ((l16 * 128 + kkv * 32 + g * 8) ^ ((l16 & 7) << 3)));
      bf16x8 vf[4];
#pragma unroll
      for (int nd = 0; nd < 4; nd++)
        vf[nd] = *(const bf16x8*)(vt + (size_t)(nd * 16 + l16) * 1024 + kv0 + kkv * 32 + g * 8);
      __builtin_amdgcn_s_setprio(1);
#pragma unroll
      for (int nd = 0; nd < 4; nd++)
        oacc[nd] = __builtin_amdgcn_mfma_f32_16x16x32_bf16(vf[nd], pf, oacc[nd], 0, 0, 0);
      __builtin_amdgcn_s_setprio(0);
    }
  }

  {
    const int q = q0 + w * 16 + l16;
    bf16* ob = aout + (size_t)(b * 1024 + q) * 768 + h * 64 + g * 4;
#pragma unroll
    for (int nd = 0; nd < 4; nd++) {
      bf16x4 o4;
      o4[0] = (bf16)oacc[nd][0]; o4[1] = (bf16)oacc[nd][1];
      o4[2] = (bf16)oacc[nd][2]; o4[3] = (bf16)oacc[nd][3];
      *(bf16x4*)(ob + nd * 16) = o4;
    }
  }
}

// ---------------- host ----------------
extern "C" void kernel_launch(void* const* d_in, const int* in_sizes, int n_in,
                              void* d_out, int out_size, void* d_ws, size_t ws_size,
                              hipStream_t stream) {
  (void)in_sizes; (void)n_in; (void)out_size; (void)ws_size;
  const float* x = (const float*)d_in[0];
#define IN(d, i) ((const float*)d_in[1 + (d) * 12 + (i)])
  float* outF = (float*)d_out;
  float* attnp[2] = {outF + 3145728, outF + 3145728 + 50331648};

  // allow 128 KiB dynamic LDS for the 256^2 GEMM (idempotent, capture-safe)
  const int kLds = 131072;
  hipFuncSetAttribute((const void*)gemm256_k<0>,
                      hipFuncAttributeMaxDynamicSharedMemorySize, kLds);
  hipFuncSetAttribute((const void*)gemm256_k<1>,
                      hipFuncAttributeMaxDynamicSharedMemorySize, kLds);
  hipFuncSetAttribute((const void*)gemm256_k<4>,
                      hipFuncAttributeMaxDynamicSharedMemorySize, kLds);

  char* p = (char*)d_ws;
  auto alloc = [&](size_t bytes) { void* r = p; p += bytes; return r; };
  bf16 *qkv_wt[2], *proj_wt[2], *w1t[2], *w2t[2];
  for (int d = 0; d < 2; d++) {
    qkv_wt[d]  = (bf16*)alloc((size_t)2304 * 768 * 2);
    proj_wt[d] = (bf16*)alloc((size_t)768 * 768 * 2);
    w1t[d]     = (bf16*)alloc((size_t)3072 * 768 * 2);
    w2t[d]     = (bf16*)alloc((size_t)768 * 3072 * 2);
  }
  // hbuf+qkvb form one contiguous 25.17 MB region; reused as up to 4 bf16
  // split-K partials (4 x 3145728 elems) while both buffers are dead.
  bf16*  hbuf = (bf16*)alloc((size_t)4096 * 768 * 2);
  bf16*  qkvb = (bf16*)alloc((size_t)4096 * 2304 * 2);
  bf16*  pbuf = hbuf;
  bf16*  vT   = (bf16*)alloc((size_t)48 * 64 * 1024 * 2);
  bf16*  aout = (bf16*)alloc((size_t)4096 * 768 * 2);
  bf16*  hid  = (bf16*)alloc((size_t)4096 * 3072 * 2);
  float* xa   = (float*)alloc((size_t)4096 * 768 * 4);
  float* xb   = (float*)alloc((size_t)4096 * 768 * 4);

  transpose_all_k<<<14848, 256, 0, stream>>>(
      IN(0, 0), qkv_wt[0], IN(0, 2), proj_wt[0], IN(0, 8), w1t[0], IN(0, 10), w2t[0],
      IN(1, 0), qkv_wt[1], IN(1, 2), proj_wt[1], IN(1, 8), w1t[1], IN(1, 10), w2t[1],
      x, IN(0, 4), IN(0, 5), hbuf);

  // ---- layer 0 attention: xa = x + attn0(hbuf); also LN1_1(xa) -> hbuf ----
  gemm256_k<0><<<dim3(9, 16), 512, kLds, stream>>>(hbuf, 768, qkv_wt[0], 768, IN(0, 1),
                                                   qkvb, 2304, 768, vT, 0);
  fattn_k<<<768, 256, 0, stream>>>(qkvb, vT, attnp[0], aout);
  gemm256_k<4><<<dim3(3, 16, 2), 512, kLds, stream>>>(aout, 768, proj_wt[0], 768, nullptr,
                                                      pbuf, 768, 384, nullptr, 3145728);
  reduce_ln_k<2, 0, true><<<1024, 256, 0, stream>>>(pbuf, IN(0, 3), x, nullptr,
                                                    xa, IN(1, 4), IN(1, 5), hbuf);
  // ---- layer 1 attention: xb = xa + attn1(hbuf); also LN2_1(xb) -> hbuf ----
  gemm256_k<0><<<dim3(9, 16), 512, kLds, stream>>>(hbuf, 768, qkv_wt[1], 768, IN(1, 1),
                                                   qkvb, 2304, 768, vT, 0);
  fattn_k<<<768, 256, 0, stream>>>(qkvb, vT, attnp[1], aout);
  gemm256_k<4><<<dim3(3, 16, 2), 512, kLds, stream>>>(aout, 768, proj_wt[1], 768, nullptr,
                                                      pbuf, 768, 384, nullptr, 3145728);
  reduce_ln_k<2, 0, true><<<1024, 256, 0, stream>>>(pbuf, IN(1, 3), xa, nullptr,
                                                    xb, IN(1, 6), IN(1, 7), hbuf);
  // ---- layer 1 MLP + blend: xa = 0.5*(xa + xb + mlp1(hbuf)); LN2_0(xa) -> hbuf ----
  gemm256_k<1><<<dim3(12, 16), 512, kLds, stream>>>(hbuf, 768, w1t[1], 768, IN(1, 9),
                                                    hid, 3072, 768, nullptr, 0);
  gemm256_k<4><<<dim3(3, 16, 4), 512, kLds, stream>>>(hid, 3072, w2t[1], 3072, nullptr,
                                                      pbuf, 768, 768, nullptr, 3145728);
  reduce_ln_k<4, 1, true><<<1024, 256, 0, stream>>>(pbuf, IN(1, 11), xb, xa,
                                                    xa, IN(0, 6), IN(0, 7), hbuf);
  // ---- layer 0 MLP: out = xa + mlp0(hbuf) ----
  gemm256_k<1><<<dim3(12, 16), 512, kLds, stream>>>(hbuf, 768, w1t[0], 768, IN(0, 9),
                                                    hid, 3072, 768, nullptr, 0);
  gemm256_k<4><<<dim3(3, 16, 4), 512, kLds, stream>>>(hid, 3072, w2t[0], 3072, nullptr,
                                                      pbuf, 768, 768, nullptr, 3145728);
  reduce_ln_k<4, 0, false><<<1024, 256, 0, stream>>>(pbuf, IN(0, 11), xa, nullptr,
                                                     outF, nullptr, nullptr, nullptr);
#undef IN
}

// Round 11
// 432.230 us; speedup vs baseline: 1.2227x; 1.1038x over previous
//
#include <hip/hip_runtime.h>
#include <hip/hip_bf16.h>
#include <stdint.h>

typedef __bf16 bf16;
typedef __bf16 bf16x8 __attribute__((ext_vector_type(8)));
typedef __bf16 bf16x4 __attribute__((ext_vector_type(4)));
typedef float  f32x4  __attribute__((ext_vector_type(4)));

#define GLOAD16(gsrc, ldst)                                                        \
  __builtin_amdgcn_global_load_lds(                                               \
      (const __attribute__((address_space(1))) void*)(gsrc),                      \
      (__attribute__((address_space(3))) void*)(ldst), 16, 0, 0)

__device__ __forceinline__ float gelu_f(float v) {
  return 0.5f * v * (1.0f + erff(v * 0.70710678118654752f));
}

// ---- batched transpose+cast for all 8 weights  +  fused ln0 (blocks >= 13824) ----
__global__ __launch_bounds__(256) void transpose_all_k(
    const float* __restrict__ qw0, bf16* __restrict__ qt0,
    const float* __restrict__ pw0, bf16* __restrict__ pt0,
    const float* __restrict__ w10, bf16* __restrict__ t10,
    const float* __restrict__ w20, bf16* __restrict__ t20,
    const float* __restrict__ qw1, bf16* __restrict__ qt1,
    const float* __restrict__ pw1, bf16* __restrict__ pt1,
    const float* __restrict__ w11, bf16* __restrict__ t11,
    const float* __restrict__ w21, bf16* __restrict__ t21,
    const float* __restrict__ x, const float* __restrict__ lng,
    const float* __restrict__ lnb, bf16* __restrict__ lnout) {
  int i = blockIdx.x;
  if (i >= 13824) {
    const int token = (i - 13824) * 4 + (threadIdx.x >> 6);
    const int lane  = threadIdx.x & 63;
    const float4* xp = (const float4*)(x + (size_t)token * 768);
    float4 v[3];
    float s = 0.f, ss = 0.f;
#pragma unroll
    for (int j = 0; j < 3; j++) {
      v[j] = xp[lane + j * 64];
      s  += v[j].x + v[j].y + v[j].z + v[j].w;
      ss += v[j].x * v[j].x + v[j].y * v[j].y + v[j].z * v[j].z + v[j].w * v[j].w;
    }
#pragma unroll
    for (int o = 32; o > 0; o >>= 1) { s += __shfl_xor(s, o); ss += __shfl_xor(ss, o); }
    const float mu  = s * (1.f / 768.f);
    const float var = ss * (1.f / 768.f) - mu * mu;
    const float r   = rsqrtf(var + 1e-5f);
#pragma unroll
    for (int j = 0; j < 3; j++) {
      const int c0 = (lane + j * 64) * 4;
      bf16x4 o4;
      o4[0] = (bf16)((v[j].x - mu) * r * lng[c0 + 0] + lnb[c0 + 0]);
      o4[1] = (bf16)((v[j].y - mu) * r * lng[c0 + 1] + lnb[c0 + 1]);
      o4[2] = (bf16)((v[j].z - mu) * r * lng[c0 + 2] + lnb[c0 + 2]);
      o4[3] = (bf16)((v[j].w - mu) * r * lng[c0 + 3] + lnb[c0 + 3]);
      *(bf16x4*)(lnout + (size_t)token * 768 + c0) = o4;
    }
    return;
  }
  __shared__ float tile[32][33];
  const int d = (i >= 6912) ? 1 : 0;
  i -= d * 6912;
  const float* W; bf16* Wt; int K, N, nt;
  if (i < 1728)      { W = d ? qw1 : qw0; Wt = d ? qt1 : qt0; K = 768;  N = 2304; nt = 72; }
  else if (i < 2304) { i -= 1728; W = d ? pw1 : pw0; Wt = d ? pt1 : pt0; K = 768; N = 768; nt = 24; }
  else if (i < 4608) { i -= 2304; W = d ? w11 : w10; Wt = d ? t11 : t10; K = 768; N = 3072; nt = 96; }
  else               { i -= 4608; W = d ? w21 : w20; Wt = d ? t21 : t20; K = 3072; N = 768; nt = 24; }
  const int n0 = (i % nt) * 32, k0 = (i / nt) * 32;
  const int tx = threadIdx.x & 31, ty = threadIdx.x >> 5;
#pragma unroll
  for (int j = ty; j < 32; j += 8)
    tile[j][tx] = W[(size_t)(k0 + j) * N + n0 + tx];
  __syncthreads();
#pragma unroll
  for (int j = ty; j < 32; j += 8)
    Wt[(size_t)(n0 + j) * K + k0 + tx] = (bf16)tile[tx][j];
}

// ======== 256xBN-tile 8-wave deep-pipelined GEMM: C = A[M,K] @ Bt[N,K]^T ========
// BN = NF*64 (NF 16-col frags per wave; 4 waves across N). BM=256, BK=64.
// Double-buffered LDS (A 64KB + B NF*16KB*2), XOR-swizzled (16B slot ^ row&7),
// pre-swizzled gload source + swizzled ds_read. Group j reads buf[j&1] while
// staging K-tile j+1 into the other buffer; one __syncthreads per K-tile is
// both the vmcnt(0) visibility gate and the overwrite gate (race-free).
// EPI 0: bf16 = acc+bias, plus V-transpose side-write for cols>=1536
// EPI 1: bf16 = gelu(acc+bias)
// EPI 4: bf16 partial (split-K over blockIdx.z, no bias), stride pstride
template <int EPI, int NF>
__global__ __launch_bounds__(512, 2) void gemm256_k(
    const bf16* __restrict__ A, int lda,
    const bf16* __restrict__ Bt, int ldb,
    const float* __restrict__ bias,
    void* __restrict__ outp, int ldc, int K, bf16* __restrict__ vtout,
    size_t pstride) {
  extern __shared__ __align__(16) bf16 smem[];
  bf16* As = smem;                 // [2][256][64]
  bf16* Bs = smem + 32768;         // [2][NF*64][64]
  const int BROWS = NF * 64;

  const int t = threadIdx.x, wave = t >> 6, lane = t & 63;
  const int g = lane >> 4, l16 = lane & 15;
  const int wm = wave >> 2, wn = wave & 3;
  const int row0 = blockIdx.y * 256, col0 = blockIdx.x * (NF * 64);
  const int koff = (EPI == 4) ? blockIdx.z * K : 0;
  const int KT = K >> 6;

  f32x4 acc[8][NF];
#pragma unroll
  for (int m = 0; m < 8; m++)
#pragma unroll
    for (int n = 0; n < NF; n++) acc[m][n] = f32x4{0.f, 0.f, 0.f, 0.f};

  const int s_r = t >> 3, s_sl = t & 7;

  auto stage = [&](int kt, int tb) {
    const int k0 = koff + (kt << 6);
#pragma unroll
    for (int l = 0; l < 4; ++l) {
      const int row = l * 64 + s_r;
      const int swz = (s_sl ^ (row & 7)) << 3;
      GLOAD16(A + (size_t)(row0 + row) * lda + k0 + swz,
              As + tb * 16384 + row * 64 + (s_sl << 3));
    }
#pragma unroll
    for (int l = 0; l < NF; ++l) {
      const int row = l * 64 + s_r;
      const int swz = (s_sl ^ (row & 7)) << 3;
      GLOAD16(Bt + (size_t)(col0 + row) * ldb + k0 + swz,
              Bs + tb * (BROWS * 64) + row * 64 + (s_sl << 3));
    }
  };

  stage(0, 0);
  __syncthreads();

  for (int j = 0; j < KT; ++j) {
    const int p = j & 1;
    if (j + 1 < KT) stage(j + 1, p ^ 1);

    bf16x8 bfr[NF][2];
#pragma unroll
    for (int n = 0; n < NF; ++n)
#pragma unroll
      for (int kk = 0; kk < 2; ++kk) {
        const int r = wn * (NF * 16) + n * 16 + l16;
        bfr[n][kk] = *(const bf16x8*)(Bs + p * (BROWS * 64) + r * 64 +
                                      ((((kk << 2) + g) ^ (r & 7)) << 3));
      }
#pragma unroll
    for (int quad = 0; quad < 4; ++quad) {
      bf16x8 af[2][2];
#pragma unroll
      for (int mm = 0; mm < 2; ++mm)
#pragma unroll
        for (int kk = 0; kk < 2; ++kk) {
          const int r = wm * 128 + (quad * 2 + mm) * 16 + l16;
          af[mm][kk] = *(const bf16x8*)(As + p * 16384 + r * 64 +
                                        ((((kk << 2) + g) ^ (r & 7)) << 3));
        }
      __builtin_amdgcn_s_barrier();
      __builtin_amdgcn_s_setprio(1);
#pragma unroll
      for (int mm = 0; mm < 2; ++mm)
#pragma unroll
        for (int n = 0; n < NF; ++n)
#pragma unroll
          for (int kk = 0; kk < 2; ++kk)
            acc[quad * 2 + mm][n] = __builtin_amdgcn_mfma_f32_16x16x32_bf16(
                bfr[n][kk], af[mm][kk], acc[quad * 2 + mm][n], 0, 0, 0);
      __builtin_amdgcn_s_setprio(0);
    }
    __syncthreads();   // gate: vmcnt(0)+lgkmcnt(0)+barrier (visibility + overwrite)
  }

  // epilogue: row = row0 + wm*128 + m*16 + l16 ; col = col0 + wn*NF*16 + n*16 + g*4
  const int rowb = row0 + wm * 128 + l16;
  const int colb = col0 + wn * (NF * 16) + (g << 2);
  bf16* outb = (bf16*)outp;
  if constexpr (EPI == 4) outb += (size_t)blockIdx.z * pstride;
#pragma unroll
  for (int m = 0; m < 8; ++m) {
    const int row = rowb + m * 16;
#pragma unroll
    for (int n = 0; n < NF; ++n) {
      const int c0 = colb + n * 16;
      f32x4 v = acc[m][n];
      if constexpr (EPI != 4) {
        const float4 b4 = *(const float4*)(bias + c0);
        v[0] += b4.x; v[1] += b4.y; v[2] += b4.z; v[3] += b4.w;
      }
      if constexpr (EPI == 1) {
        v[0] = gelu_f(v[0]); v[1] = gelu_f(v[1]);
        v[2] = gelu_f(v[2]); v[3] = gelu_f(v[3]);
      }
      bf16x4 o4;
      o4[0] = (bf16)v[0]; o4[1] = (bf16)v[1]; o4[2] = (bf16)v[2]; o4[3] = (bf16)v[3];
      *(bf16x4*)(outb + (size_t)row * ldc + c0) = o4;
      if constexpr (EPI == 0) {
        if (c0 >= 1536) {   // fused V-transpose side-write
          const int bq = row >> 10, q = row & 1023;
          const int hd = c0 - 1536, h = hd >> 6, dd = hd & 63;
          bf16* vb = vtout + (size_t)(bq * 12 + h) * 65536 + (size_t)dd * 1024 + q;
          vb[0] = o4[0]; vb[1024] = o4[1]; vb[2048] = o4[2]; vb[3072] = o4[3];
        }
      }
    }
  }
}

// ------ split-K reduce + optional fused LayerNorm of the result ------
template <int NP, int MODE, bool LN>
__global__ __launch_bounds__(256) void reduce_ln_k(
    const bf16* __restrict__ pbuf, const float* __restrict__ bias,
    const float* __restrict__ res, const float* __restrict__ res2,
    float* __restrict__ xout, const float* __restrict__ g,
    const float* __restrict__ b, bf16* __restrict__ lnout) {
  const int token = blockIdx.x * 4 + (threadIdx.x >> 6);
  const int lane  = threadIdx.x & 63;
  float o[12];
  float s = 0.f, ss = 0.f;
#pragma unroll
  for (int j = 0; j < 3; j++) {
    const int c0 = (lane + j * 64) * 4;
    const size_t idx = (size_t)token * 768 + c0;
    const float4 b4 = *(const float4*)(bias + c0);
    float a0 = b4.x, a1 = b4.y, a2 = b4.z, a3 = b4.w;
#pragma unroll
    for (int sp = 0; sp < NP; sp++) {
      const bf16x4 pp = *(const bf16x4*)(pbuf + (size_t)sp * 3145728 + idx);
      a0 += (float)pp[0]; a1 += (float)pp[1]; a2 += (float)pp[2]; a3 += (float)pp[3];
    }
    const float4 r4 = *(const float4*)(res + idx);
    float4 ov;
    if constexpr (MODE == 0) {
      ov.x = a0 + r4.x; ov.y = a1 + r4.y; ov.z = a2 + r4.z; ov.w = a3 + r4.w;
    } else {
      const float4 r2 = *(const float4*)(res2 + idx);
      ov.x = 0.5f * (a0 + r4.x + r2.x); ov.y = 0.5f * (a1 + r4.y + r2.y);
      ov.z = 0.5f * (a2 + r4.z + r2.z); ov.w = 0.5f * (a3 + r4.w + r2.w);
    }
    *(float4*)(xout + idx) = ov;
    o[j * 4 + 0] = ov.x; o[j * 4 + 1] = ov.y; o[j * 4 + 2] = ov.z; o[j * 4 + 3] = ov.w;
    s  += ov.x + ov.y + ov.z + ov.w;
    ss += ov.x * ov.x + ov.y * ov.y + ov.z * ov.z + ov.w * ov.w;
  }
  if constexpr (LN) {
#pragma unroll
    for (int off = 32; off > 0; off >>= 1) { s += __shfl_xor(s, off); ss += __shfl_xor(ss, off); }
    const float mu  = s * (1.f / 768.f);
    const float var = ss * (1.f / 768.f) - mu * mu;
    const float r   = rsqrtf(var + 1e-5f);
#pragma unroll
    for (int j = 0; j < 3; j++) {
      const int c0 = (lane + j * 64) * 4;
      bf16x4 o4;
      o4[0] = (bf16)((o[j * 4 + 0] - mu) * r * g[c0 + 0] + b[c0 + 0]);
      o4[1] = (bf16)((o[j * 4 + 1] - mu) * r * g[c0 + 1] + b[c0 + 1]);
      o4[2] = (bf16)((o[j * 4 + 2] - mu) * r * g[c0 + 2] + b[c0 + 2]);
      o4[3] = (bf16)((o[j * 4 + 3] - mu) * r * g[c0 + 3] + b[c0 + 3]);
      *(bf16x4*)(lnout + (size_t)token * 768 + c0) = o4;
    }
  }
}

// ---------------- fused attention: S^T via mfma(K,Q), 2-pass softmax (no max), PV ----
__global__ __launch_bounds__(256) void fattn_k(const bf16* __restrict__ qkv,
                                               const bf16* __restrict__ vT,
                                               float* __restrict__ attn,
                                               bf16* __restrict__ aout) {
  __shared__ __align__(16) bf16 Ks[128 * 64];
  __shared__ __align__(16) bf16 Ps[4 * 16 * 128];

  const float S2 = 0.18033688011112042f;  // 0.125 * log2(e)

  const int bid = blockIdx.x;
  const int xcd = bid & 7, within = bid >> 3;
  const int bh = xcd * 6 + (within >> 4);
  const int qb = within & 15;
  const int b = bh / 12, h = bh % 12;

  const int t = threadIdx.x, w = t >> 6, lane = t & 63;
  const int g = lane >> 4, l16 = lane & 15;
  const int q0 = qb * 64;

  const bf16* qbp = qkv + (size_t)b * 1024 * 2304 + h * 64;
  const bf16* kbp = qbp + 768;
  const bf16* vt = vT + (size_t)bh * 65536;
  float* Pout = attn + (size_t)bh * 1048576;
  bf16* Pw = Ps + w * 2048;

  bf16x8 qf[2];
#pragma unroll
  for (int kk = 0; kk < 2; kk++)
    qf[kk] = *(const bf16x8*)(qbp + (size_t)(q0 + w * 16 + l16) * 2304 + kk * 32 + g * 8);

  const int kvr = t >> 3, sl = t & 7;

  float l_run = 0.f;

  for (int kv0 = 0; kv0 < 1024; kv0 += 128) {
#pragma unroll
    for (int i = 0; i < 4; i++) {
      const int kvl = i * 32 + kvr;
      GLOAD16(kbp + (size_t)(kv0 + kvl) * 2304 + (sl ^ (kvl & 7)) * 8,
              Ks + i * 2048 + t * 8);
    }
    __syncthreads();
    f32x4 st[8];
#pragma unroll
    for (int mk = 0; mk < 8; mk++) st[mk] = f32x4{0.f, 0.f, 0.f, 0.f};
    __builtin_amdgcn_s_setprio(1);
#pragma unroll
    for (int kk = 0; kk < 2; kk++) {
#pragma unroll
      for (int mk = 0; mk < 8; mk++) {
        const int kv = mk * 16 + l16;
        const bf16x8 kf = *(const bf16x8*)(Ks + ((kv * 64 + kk * 32 + g * 8) ^ ((kv & 7) << 3)));
        st[mk] = __builtin_amdgcn_mfma_f32_16x16x32_bf16(kf, qf[kk], st[mk], 0, 0, 0);
      }
    }
    __builtin_amdgcn_s_setprio(0);
    __syncthreads();
    float sum = 0.f;
#pragma unroll
    for (int mk = 0; mk < 8; mk++)
#pragma unroll
      for (int r = 0; r < 4; r++) sum += exp2f(st[mk][r] * S2);
    sum += __shfl_xor(sum, 16);
    sum += __shfl_xor(sum, 32);
    l_run += sum;
  }

  const float invl = 1.f / l_run;

  f32x4 oacc[4];
#pragma unroll
  for (int nd = 0; nd < 4; nd++) oacc[nd] = f32x4{0.f, 0.f, 0.f, 0.f};

  for (int kv0 = 0; kv0 < 1024; kv0 += 128) {
#pragma unroll
    for (int i = 0; i < 4; i++) {
      const int kvl = i * 32 + kvr;
      GLOAD16(kbp + (size_t)(kv0 + kvl) * 2304 + (sl ^ (kvl & 7)) * 8,
              Ks + i * 2048 + t * 8);
    }
    __syncthreads();
    f32x4 st[8];
#pragma unroll
    for (int mk = 0; mk < 8; mk++) st[mk] = f32x4{0.f, 0.f, 0.f, 0.f};
    __builtin_amdgcn_s_setprio(1);
#pragma unroll
    for (int kk = 0; kk < 2; kk++) {
#pragma unroll
      for (int mk = 0; mk < 8; mk++) {
        const int kv = mk * 16 + l16;
        const bf16x8 kf = *(const bf16x8*)(Ks + ((kv * 64 + kk * 32 + g * 8) ^ ((kv & 7) << 3)));
        st[mk] = __builtin_amdgcn_mfma_f32_16x16x32_bf16(kf, qf[kk], st[mk], 0, 0, 0);
      }
    }
    __builtin_amdgcn_s_setprio(0);
    __syncthreads();

    const int q = q0 + w * 16 + l16;
#pragma unroll
    for (int mk = 0; mk < 8; mk++) {
      f32x4 pv;
      pv[0] = exp2f(st[mk][0] * S2) * invl;
      pv[1] = exp2f(st[mk][1] * S2) * invl;
      pv[2] = exp2f(st[mk][2] * S2) * invl;
      pv[3] = exp2f(st[mk][3] * S2) * invl;
      __builtin_nontemporal_store(pv, (f32x4*)(Pout + (size_t)q * 1024 + kv0 + mk * 16 + g * 4));
      bf16x4 pb;
      pb[0] = (bf16)pv[0]; pb[1] = (bf16)pv[1]; pb[2] = (bf16)pv[2]; pb[3] = (bf16)pv[3];
      *(bf16x4*)(Pw + ((l16 * 128 + mk * 16 + g * 4) ^ ((l16 & 7) << 3))) = pb;
    }

#pragma unroll
    for (int kkv = 0; kkv < 4; kkv++) {
      const bf16x8 pf = *(const bf16x8*)(Pw + ((l16 * 128 + kkv * 32 + g * 8) ^ ((l16 & 7) << 3)));
      bf16x8 vf[4];
#pragma unroll
      for (int nd = 0; nd < 4; nd++)
        vf[nd] = *(const bf16x8*)(vt + (size_t)(nd * 16 + l16) * 1024 + kv0 + kkv * 32 + g * 8);
      __builtin_amdgcn_s_setprio(1);
#pragma unroll
      for (int nd = 0; nd < 4; nd++)
        oacc[nd] = __builtin_amdgcn_mfma_f32_16x16x32_bf16(vf[nd], pf, oacc[nd], 0, 0, 0);
      __builtin_amdgcn_s_setprio(0);
    }
  }

  {
    const int q = q0 + w * 16 + l16;
    bf16* ob = aout + (size_t)(b * 1024 + q) * 768 + h * 64 + g * 4;
#pragma unroll
    for (int nd = 0; nd < 4; nd++) {
      bf16x4 o4;
      o4[0] = (bf16)oacc[nd][0]; o4[1] = (bf16)oacc[nd][1];
      o4[2] = (bf16)oacc[nd][2]; o4[3] = (bf16)oacc[nd][3];
      *(bf16x4*)(ob + nd * 16) = o4;
    }
  }
}

// ---------------- host ----------------
extern "C" void kernel_launch(void* const* d_in, const int* in_sizes, int n_in,
                              void* d_out, int out_size, void* d_ws, size_t ws_size,
                              hipStream_t stream) {
  (void)in_sizes; (void)n_in; (void)out_size; (void)ws_size;
  const float* x = (const float*)d_in[0];
#define IN(d, i) ((const float*)d_in[1 + (d) * 12 + (i)])
  float* outF = (float*)d_out;
  float* attnp[2] = {outF + 3145728, outF + 3145728 + 50331648};

  // 112 KiB dynamic LDS for the 256x192 GEMM (idempotent, capture-safe)
  const int kLds = 114688;
  hipFuncSetAttribute((const void*)gemm256_k<0, 3>,
                      hipFuncAttributeMaxDynamicSharedMemorySize, kLds);
  hipFuncSetAttribute((const void*)gemm256_k<1, 3>,
                      hipFuncAttributeMaxDynamicSharedMemorySize, kLds);
  hipFuncSetAttribute((const void*)gemm256_k<4, 3>,
                      hipFuncAttributeMaxDynamicSharedMemorySize, kLds);

  char* p = (char*)d_ws;
  auto alloc = [&](size_t bytes) { void* r = p; p += bytes; return r; };
  bf16 *qkv_wt[2], *proj_wt[2], *w1t[2], *w2t[2];
  for (int d = 0; d < 2; d++) {
    qkv_wt[d]  = (bf16*)alloc((size_t)2304 * 768 * 2);
    proj_wt[d] = (bf16*)alloc((size_t)768 * 768 * 2);
    w1t[d]     = (bf16*)alloc((size_t)3072 * 768 * 2);
    w2t[d]     = (bf16*)alloc((size_t)768 * 3072 * 2);
  }
  // hbuf+qkvb form one contiguous 25.17 MB region; reused as up to 4 bf16
  // split-K partials (4 x 3145728 elems) while both buffers are dead.
  bf16*  hbuf = (bf16*)alloc((size_t)4096 * 768 * 2);
  bf16*  qkvb = (bf16*)alloc((size_t)4096 * 2304 * 2);
  bf16*  pbuf = hbuf;
  bf16*  vT   = (bf16*)alloc((size_t)48 * 64 * 1024 * 2);
  bf16*  aout = (bf16*)alloc((size_t)4096 * 768 * 2);
  bf16*  hid  = (bf16*)alloc((size_t)4096 * 3072 * 2);
  float* xa   = (float*)alloc((size_t)4096 * 768 * 4);
  float* xb   = (float*)alloc((size_t)4096 * 768 * 4);

  transpose_all_k<<<14848, 256, 0, stream>>>(
      IN(0, 0), qkv_wt[0], IN(0, 2), proj_wt[0], IN(0, 8), w1t[0], IN(0, 10), w2t[0],
      IN(1, 0), qkv_wt[1], IN(1, 2), proj_wt[1], IN(1, 8), w1t[1], IN(1, 10), w2t[1],
      x, IN(0, 4), IN(0, 5), hbuf);

  // ---- layer 0 attention: xa = x + attn0(hbuf); also LN1_1(xa) -> hbuf ----
  gemm256_k<0, 3><<<dim3(12, 16), 512, kLds, stream>>>(hbuf, 768, qkv_wt[0], 768, IN(0, 1),
                                                       qkvb, 2304, 768, vT, 0);
  fattn_k<<<768, 256, 0, stream>>>(qkvb, vT, attnp[0], aout);
  gemm256_k<4, 3><<<dim3(4, 16, 4), 512, kLds, stream>>>(aout, 768, proj_wt[0], 768, nullptr,
                                                         pbuf, 768, 192, nullptr, 3145728);
  reduce_ln_k<4, 0, true><<<1024, 256, 0, stream>>>(pbuf, IN(0, 3), x, nullptr,
                                                    xa, IN(1, 4), IN(1, 5), hbuf);
  // ---- layer 1 attention: xb = xa + attn1(hbuf); also LN2_1(xb) -> hbuf ----
  gemm256_k<0, 3><<<dim3(12, 16), 512, kLds, stream>>>(hbuf, 768, qkv_wt[1], 768, IN(1, 1),
                                                       qkvb, 2304, 768, vT, 0);
  fattn_k<<<768, 256, 0, stream>>>(qkvb, vT, attnp[1], aout);
  gemm256_k<4, 3><<<dim3(4, 16, 4), 512, kLds, stream>>>(aout, 768, proj_wt[1], 768, nullptr,
                                                         pbuf, 768, 192, nullptr, 3145728);
  reduce_ln_k<4, 0, true><<<1024, 256, 0, stream>>>(pbuf, IN(1, 3), xa, nullptr,
                                                    xb, IN(1, 6), IN(1, 7), hbuf);
  // ---- layer 1 MLP + blend: xa = 0.5*(xa + xb + mlp1(hbuf)); LN2_0(xa) -> hbuf ----
  gemm256_k<1, 3><<<dim3(16, 16), 512, kLds, stream>>>(hbuf, 768, w1t[1], 768, IN(1, 9),
                                                       hid, 3072, 768, nullptr, 0);
  gemm256_k<4, 3><<<dim3(4, 16, 4), 512, kLds, stream>>>(hid, 3072, w2t[1], 3072, nullptr,
                                                         pbuf, 768, 768, nullptr, 3145728);
  reduce_ln_k<4, 1, true><<<1024, 256, 0, stream>>>(pbuf, IN(1, 11), xb, xa,
                                                    xa, IN(0, 6), IN(0, 7), hbuf);
  // ---- layer 0 MLP: out = xa + mlp0(hbuf) ----
  gemm256_k<1, 3><<<dim3(16, 16), 512, kLds, stream>>>(hbuf, 768, w1t[0], 768, IN(0, 9),
                                                       hid, 3072, 768, nullptr, 0);
  gemm256_k<4, 3><<<dim3(4, 16, 4), 512, kLds, stream>>>(hid, 3072, w2t[0], 3072, nullptr,
                                                         pbuf, 768, 768, nullptr, 3145728);
  reduce_ln_k<4, 0, false><<<1024, 256, 0, stream>>>(pbuf, IN(0, 11), xa, nullptr,
                                                     outF, nullptr, nullptr, nullptr);
#undef IN
}

// Round 12
// 418.474 us; speedup vs baseline: 1.2629x; 1.0329x over previous
//
#include <hip/hip_runtime.h>
#include <hip/hip_bf16.h>
#include <stdint.h>

typedef __bf16 bf16;
typedef __bf16 bf16x8 __attribute__((ext_vector_type(8)));
typedef __bf16 bf16x4 __attribute__((ext_vector_type(4)));
typedef float  f32x4  __attribute__((ext_vector_type(4)));

#define GLOAD16(gsrc, ldst)                                                        \
  __builtin_amdgcn_global_load_lds(                                               \
      (const __attribute__((address_space(1))) void*)(gsrc),                      \
      (__attribute__((address_space(3))) void*)(ldst), 16, 0, 0)

__device__ __forceinline__ float gelu_f(float v) {
  return 0.5f * v * (1.0f + erff(v * 0.70710678118654752f));
}

// ---- batched transpose+cast for all 8 weights  +  fused ln0 (blocks >= 13824) ----
__global__ __launch_bounds__(256) void transpose_all_k(
    const float* __restrict__ qw0, bf16* __restrict__ qt0,
    const float* __restrict__ pw0, bf16* __restrict__ pt0,
    const float* __restrict__ w10, bf16* __restrict__ t10,
    const float* __restrict__ w20, bf16* __restrict__ t20,
    const float* __restrict__ qw1, bf16* __restrict__ qt1,
    const float* __restrict__ pw1, bf16* __restrict__ pt1,
    const float* __restrict__ w11, bf16* __restrict__ t11,
    const float* __restrict__ w21, bf16* __restrict__ t21,
    const float* __restrict__ x, const float* __restrict__ lng,
    const float* __restrict__ lnb, bf16* __restrict__ lnout) {
  int i = blockIdx.x;
  if (i >= 13824) {
    const int token = (i - 13824) * 4 + (threadIdx.x >> 6);
    const int lane  = threadIdx.x & 63;
    const float4* xp = (const float4*)(x + (size_t)token * 768);
    float4 v[3];
    float s = 0.f, ss = 0.f;
#pragma unroll
    for (int j = 0; j < 3; j++) {
      v[j] = xp[lane + j * 64];
      s  += v[j].x + v[j].y + v[j].z + v[j].w;
      ss += v[j].x * v[j].x + v[j].y * v[j].y + v[j].z * v[j].z + v[j].w * v[j].w;
    }
#pragma unroll
    for (int o = 32; o > 0; o >>= 1) { s += __shfl_xor(s, o); ss += __shfl_xor(ss, o); }
    const float mu  = s * (1.f / 768.f);
    const float var = ss * (1.f / 768.f) - mu * mu;
    const float r   = rsqrtf(var + 1e-5f);
#pragma unroll
    for (int j = 0; j < 3; j++) {
      const int c0 = (lane + j * 64) * 4;
      bf16x4 o4;
      o4[0] = (bf16)((v[j].x - mu) * r * lng[c0 + 0] + lnb[c0 + 0]);
      o4[1] = (bf16)((v[j].y - mu) * r * lng[c0 + 1] + lnb[c0 + 1]);
      o4[2] = (bf16)((v[j].z - mu) * r * lng[c0 + 2] + lnb[c0 + 2]);
      o4[3] = (bf16)((v[j].w - mu) * r * lng[c0 + 3] + lnb[c0 + 3]);
      *(bf16x4*)(lnout + (size_t)token * 768 + c0) = o4;
    }
    return;
  }
  __shared__ float tile[32][33];
  const int d = (i >= 6912) ? 1 : 0;
  i -= d * 6912;
  const float* W; bf16* Wt; int K, N, nt;
  if (i < 1728)      { W = d ? qw1 : qw0; Wt = d ? qt1 : qt0; K = 768;  N = 2304; nt = 72; }
  else if (i < 2304) { i -= 1728; W = d ? pw1 : pw0; Wt = d ? pt1 : pt0; K = 768; N = 768; nt = 24; }
  else if (i < 4608) { i -= 2304; W = d ? w11 : w10; Wt = d ? t11 : t10; K = 768; N = 3072; nt = 96; }
  else               { i -= 4608; W = d ? w21 : w20; Wt = d ? t21 : t20; K = 3072; N = 768; nt = 24; }
  const int n0 = (i % nt) * 32, k0 = (i / nt) * 32;
  const int tx = threadIdx.x & 31, ty = threadIdx.x >> 5;
#pragma unroll
  for (int j = ty; j < 32; j += 8)
    tile[j][tx] = W[(size_t)(k0 + j) * N + n0 + tx];
  __syncthreads();
#pragma unroll
  for (int j = ty; j < 32; j += 8)
    Wt[(size_t)(n0 + j) * K + k0 + tx] = (bf16)tile[tx][j];
}

// ======== 256xBN-tile 8-wave deep-pipelined GEMM: C = A[M,K] @ Bt[N,K]^T ========
template <int EPI, int NF>
__global__ __launch_bounds__(512, 2) void gemm256_k(
    const bf16* __restrict__ A, int lda,
    const bf16* __restrict__ Bt, int ldb,
    const float* __restrict__ bias,
    void* __restrict__ outp, int ldc, int K, bf16* __restrict__ vtout,
    size_t pstride) {
  extern __shared__ __align__(16) bf16 smem[];
  bf16* As = smem;                 // [2][256][64]
  bf16* Bs = smem + 32768;         // [2][NF*64][64]
  const int BROWS = NF * 64;

  const int t = threadIdx.x, wave = t >> 6, lane = t & 63;
  const int g = lane >> 4, l16 = lane & 15;
  const int wm = wave >> 2, wn = wave & 3;
  const int row0 = blockIdx.y * 256, col0 = blockIdx.x * (NF * 64);
  const int koff = (EPI == 4) ? blockIdx.z * K : 0;
  const int KT = K >> 6;

  f32x4 acc[8][NF];
#pragma unroll
  for (int m = 0; m < 8; m++)
#pragma unroll
    for (int n = 0; n < NF; n++) acc[m][n] = f32x4{0.f, 0.f, 0.f, 0.f};

  const int s_r = t >> 3, s_sl = t & 7;

  auto stage = [&](int kt, int tb) {
    const int k0 = koff + (kt << 6);
#pragma unroll
    for (int l = 0; l < 4; ++l) {
      const int row = l * 64 + s_r;
      const int swz = (s_sl ^ (row & 7)) << 3;
      GLOAD16(A + (size_t)(row0 + row) * lda + k0 + swz,
              As + tb * 16384 + row * 64 + (s_sl << 3));
    }
#pragma unroll
    for (int l = 0; l < NF; ++l) {
      const int row = l * 64 + s_r;
      const int swz = (s_sl ^ (row & 7)) << 3;
      GLOAD16(Bt + (size_t)(col0 + row) * ldb + k0 + swz,
              Bs + tb * (BROWS * 64) + row * 64 + (s_sl << 3));
    }
  };

  stage(0, 0);
  __syncthreads();

  for (int j = 0; j < KT; ++j) {
    const int p = j & 1;
    if (j + 1 < KT) stage(j + 1, p ^ 1);

    bf16x8 bfr[NF][2];
#pragma unroll
    for (int n = 0; n < NF; ++n)
#pragma unroll
      for (int kk = 0; kk < 2; ++kk) {
        const int r = wn * (NF * 16) + n * 16 + l16;
        bfr[n][kk] = *(const bf16x8*)(Bs + p * (BROWS * 64) + r * 64 +
                                      ((((kk << 2) + g) ^ (r & 7)) << 3));
      }
#pragma unroll
    for (int quad = 0; quad < 4; ++quad) {
      bf16x8 af[2][2];
#pragma unroll
      for (int mm = 0; mm < 2; ++mm)
#pragma unroll
        for (int kk = 0; kk < 2; ++kk) {
          const int r = wm * 128 + (quad * 2 + mm) * 16 + l16;
          af[mm][kk] = *(const bf16x8*)(As + p * 16384 + r * 64 +
                                        ((((kk << 2) + g) ^ (r & 7)) << 3));
        }
      __builtin_amdgcn_s_barrier();
      __builtin_amdgcn_s_setprio(1);
#pragma unroll
      for (int mm = 0; mm < 2; ++mm)
#pragma unroll
        for (int n = 0; n < NF; ++n)
#pragma unroll
          for (int kk = 0; kk < 2; ++kk)
            acc[quad * 2 + mm][n] = __builtin_amdgcn_mfma_f32_16x16x32_bf16(
                bfr[n][kk], af[mm][kk], acc[quad * 2 + mm][n], 0, 0, 0);
      __builtin_amdgcn_s_setprio(0);
    }
    __syncthreads();   // gate: vmcnt(0)+lgkmcnt(0)+barrier (visibility + overwrite)
  }

  const int rowb = row0 + wm * 128 + l16;
  const int colb = col0 + wn * (NF * 16) + (g << 2);
  bf16* outb = (bf16*)outp;
  if constexpr (EPI == 4) outb += (size_t)blockIdx.z * pstride;
#pragma unroll
  for (int m = 0; m < 8; ++m) {
    const int row = rowb + m * 16;
#pragma unroll
    for (int n = 0; n < NF; ++n) {
      const int c0 = colb + n * 16;
      f32x4 v = acc[m][n];
      if constexpr (EPI != 4) {
        const float4 b4 = *(const float4*)(bias + c0);
        v[0] += b4.x; v[1] += b4.y; v[2] += b4.z; v[3] += b4.w;
      }
      if constexpr (EPI == 1) {
        v[0] = gelu_f(v[0]); v[1] = gelu_f(v[1]);
        v[2] = gelu_f(v[2]); v[3] = gelu_f(v[3]);
      }
      bf16x4 o4;
      o4[0] = (bf16)v[0]; o4[1] = (bf16)v[1]; o4[2] = (bf16)v[2]; o4[3] = (bf16)v[3];
      *(bf16x4*)(outb + (size_t)row * ldc + c0) = o4;
      if constexpr (EPI == 0) {
        if (c0 >= 1536) {   // fused V-transpose side-write
          const int bq = row >> 10, q = row & 1023;
          const int hd = c0 - 1536, h = hd >> 6, dd = hd & 63;
          bf16* vb = vtout + (size_t)(bq * 12 + h) * 65536 + (size_t)dd * 1024 + q;
          vb[0] = o4[0]; vb[1024] = o4[1]; vb[2048] = o4[2]; vb[3072] = o4[3];
        }
      }
    }
  }
}

// ------ split-K reduce + optional fused LayerNorm of the result ------
template <int NP, int MODE, bool LN>
__global__ __launch_bounds__(256) void reduce_ln_k(
    const bf16* __restrict__ pbuf, const float* __restrict__ bias,
    const float* __restrict__ res, const float* __restrict__ res2,
    float* __restrict__ xout, const float* __restrict__ g,
    const float* __restrict__ b, bf16* __restrict__ lnout) {
  const int token = blockIdx.x * 4 + (threadIdx.x >> 6);
  const int lane  = threadIdx.x & 63;
  float o[12];
  float s = 0.f, ss = 0.f;
#pragma unroll
  for (int j = 0; j < 3; j++) {
    const int c0 = (lane + j * 64) * 4;
    const size_t idx = (size_t)token * 768 + c0;
    const float4 b4 = *(const float4*)(bias + c0);
    float a0 = b4.x, a1 = b4.y, a2 = b4.z, a3 = b4.w;
#pragma unroll
    for (int sp = 0; sp < NP; sp++) {
      const bf16x4 pp = *(const bf16x4*)(pbuf + (size_t)sp * 3145728 + idx);
      a0 += (float)pp[0]; a1 += (float)pp[1]; a2 += (float)pp[2]; a3 += (float)pp[3];
    }
    const float4 r4 = *(const float4*)(res + idx);
    float4 ov;
    if constexpr (MODE == 0) {
      ov.x = a0 + r4.x; ov.y = a1 + r4.y; ov.z = a2 + r4.z; ov.w = a3 + r4.w;
    } else {
      const float4 r2 = *(const float4*)(res2 + idx);
      ov.x = 0.5f * (a0 + r4.x + r2.x); ov.y = 0.5f * (a1 + r4.y + r2.y);
      ov.z = 0.5f * (a2 + r4.z + r2.z); ov.w = 0.5f * (a3 + r4.w + r2.w);
    }
    *(float4*)(xout + idx) = ov;
    o[j * 4 + 0] = ov.x; o[j * 4 + 1] = ov.y; o[j * 4 + 2] = ov.z; o[j * 4 + 3] = ov.w;
    s  += ov.x + ov.y + ov.z + ov.w;
    ss += ov.x * ov.x + ov.y * ov.y + ov.z * ov.z + ov.w * ov.w;
  }
  if constexpr (LN) {
#pragma unroll
    for (int off = 32; off > 0; off >>= 1) { s += __shfl_xor(s, off); ss += __shfl_xor(ss, off); }
    const float mu  = s * (1.f / 768.f);
    const float var = ss * (1.f / 768.f) - mu * mu;
    const float r   = rsqrtf(var + 1e-5f);
#pragma unroll
    for (int j = 0; j < 3; j++) {
      const int c0 = (lane + j * 64) * 4;
      bf16x4 o4;
      o4[0] = (bf16)((o[j * 4 + 0] - mu) * r * g[c0 + 0] + b[c0 + 0]);
      o4[1] = (bf16)((o[j * 4 + 1] - mu) * r * g[c0 + 1] + b[c0 + 1]);
      o4[2] = (bf16)((o[j * 4 + 2] - mu) * r * g[c0 + 2] + b[c0 + 2]);
      o4[3] = (bf16)((o[j * 4 + 3] - mu) * r * g[c0 + 3] + b[c0 + 3]);
      *(bf16x4*)(lnout + (size_t)token * 768 + c0) = o4;
    }
  }
}

// ---- fused attention: S^T via mfma(K,Q), 2-pass softmax (no max), coalesced P out ----
// Pass 2 bounces normalized f32 P through a swizzled LDS tile Pf[64][128]:
// scattered MFMA-layout writes go to LDS (conflict-free), then the block copies
// Pf -> Pout in 512B-contiguous nontemporal runs. PV builds bf16 A-frags from Pf.
__global__ __launch_bounds__(256) void fattn_k(const bf16* __restrict__ qkv,
                                               const bf16* __restrict__ vT,
                                               float* __restrict__ attn,
                                               bf16* __restrict__ aout) {
  __shared__ __align__(16) bf16  Ks[128 * 64];   // 16 KB, source-swizzled
  __shared__ __align__(16) float Pf[64 * 128];   // 32 KB, slot-swizzled

  const float S2 = 0.18033688011112042f;  // 0.125 * log2(e)

  const int bid = blockIdx.x;
  const int xcd = bid & 7, within = bid >> 3;
  const int bh = xcd * 6 + (within >> 4);
  const int qb = within & 15;
  const int b = bh / 12, h = bh % 12;

  const int t = threadIdx.x, w = t >> 6, lane = t & 63;
  const int g = lane >> 4, l16 = lane & 15;
  const int q0 = qb * 64;

  const bf16* qbp = qkv + (size_t)b * 1024 * 2304 + h * 64;
  const bf16* kbp = qbp + 768;
  const bf16* vt = vT + (size_t)bh * 65536;
  float* Pout = attn + (size_t)bh * 1048576;

  bf16x8 qf[2];
#pragma unroll
  for (int kk = 0; kk < 2; kk++)
    qf[kk] = *(const bf16x8*)(qbp + (size_t)(q0 + w * 16 + l16) * 2304 + kk * 32 + g * 8);

  const int kvr = t >> 3, sl = t & 7;

  float l_run = 0.f;

  // ---------------- pass 1: row sum of exp2(S*S2) ----------------
  for (int kv0 = 0; kv0 < 1024; kv0 += 128) {
#pragma unroll
    for (int i = 0; i < 4; i++) {
      const int kvl = i * 32 + kvr;
      GLOAD16(kbp + (size_t)(kv0 + kvl) * 2304 + (sl ^ (kvl & 7)) * 8,
              Ks + i * 2048 + t * 8);
    }
    __syncthreads();
    f32x4 st[8];
#pragma unroll
    for (int mk = 0; mk < 8; mk++) st[mk] = f32x4{0.f, 0.f, 0.f, 0.f};
    __builtin_amdgcn_s_setprio(1);
#pragma unroll
    for (int kk = 0; kk < 2; kk++) {
#pragma unroll
      for (int mk = 0; mk < 8; mk++) {
        const int kv = mk * 16 + l16;
        const bf16x8 kf = *(const bf16x8*)(Ks + ((kv * 64 + kk * 32 + g * 8) ^ ((kv & 7) << 3)));
        st[mk] = __builtin_amdgcn_mfma_f32_16x16x32_bf16(kf, qf[kk], st[mk], 0, 0, 0);
      }
    }
    __builtin_amdgcn_s_setprio(0);
    __syncthreads();
    float sum = 0.f;
#pragma unroll
    for (int mk = 0; mk < 8; mk++)
#pragma unroll
      for (int r = 0; r < 4; r++) sum += exp2f(st[mk][r] * S2);
    sum += __shfl_xor(sum, 16);
    sum += __shfl_xor(sum, 32);
    l_run += sum;
  }

  const float invl = 1.f / l_run;

  f32x4 oacc[4];
#pragma unroll
  for (int nd = 0; nd < 4; nd++) oacc[nd] = f32x4{0.f, 0.f, 0.f, 0.f};

  const int ql = w * 16 + l16;      // this lane's q-row within the block
  const int cs = t & 31, rb = t >> 5;  // copy-phase mapping (32 lanes/row)

  // ---------------- pass 2: recompute S, LDS-bounce P, coalesced write, PV ----
  for (int kv0 = 0; kv0 < 1024; kv0 += 128) {
#pragma unroll
    for (int i = 0; i < 4; i++) {
      const int kvl = i * 32 + kvr;
      GLOAD16(kbp + (size_t)(kv0 + kvl) * 2304 + (sl ^ (kvl & 7)) * 8,
              Ks + i * 2048 + t * 8);
    }
    __syncthreads();
    f32x4 st[8];
#pragma unroll
    for (int mk = 0; mk < 8; mk++) st[mk] = f32x4{0.f, 0.f, 0.f, 0.f};
    __builtin_amdgcn_s_setprio(1);
#pragma unroll
    for (int kk = 0; kk < 2; kk++) {
#pragma unroll
      for (int mk = 0; mk < 8; mk++) {
        const int kv = mk * 16 + l16;
        const bf16x8 kf = *(const bf16x8*)(Ks + ((kv * 64 + kk * 32 + g * 8) ^ ((kv & 7) << 3)));
        st[mk] = __builtin_amdgcn_mfma_f32_16x16x32_bf16(kf, qf[kk], st[mk], 0, 0, 0);
      }
    }
    __builtin_amdgcn_s_setprio(0);

    // normalized P -> Pf (16B slot = (mk*4+g) ^ (ql&7); bijective per row)
#pragma unroll
    for (int mk = 0; mk < 8; mk++) {
      f32x4 pv;
      pv[0] = exp2f(st[mk][0] * S2) * invl;
      pv[1] = exp2f(st[mk][1] * S2) * invl;
      pv[2] = exp2f(st[mk][2] * S2) * invl;
      pv[3] = exp2f(st[mk][3] * S2) * invl;
      *(f32x4*)(Pf + ql * 128 + ((((mk << 2) + g) ^ (ql & 7)) << 2)) = pv;
    }
    __syncthreads();   // Pf visible to whole block; also gates Ks reads vs next loads

    // coalesced Pout copy: each instruction writes 2 rows x 512B contiguous runs
#pragma unroll
    for (int j = 0; j < 8; j++) {
      const int row = j * 8 + rb;
      const f32x4 v = *(const f32x4*)(Pf + row * 128 + ((cs ^ (row & 7)) << 2));
      __builtin_nontemporal_store(
          v, (f32x4*)(Pout + (size_t)(q0 + row) * 1024 + kv0 + (cs << 2)));
    }

    // PV: bf16 A-frags rebuilt from Pf (logical cols kkv*32+g*8 .. +8)
#pragma unroll
    for (int kkv = 0; kkv < 4; kkv++) {
      const int s0 = (kkv << 3) + (g << 1);
      const f32x4 plo = *(const f32x4*)(Pf + ql * 128 + ((s0 ^ (ql & 7)) << 2));
      const f32x4 phi = *(const f32x4*)(Pf + ql * 128 + (((s0 + 1) ^ (ql & 7)) << 2));
      bf16x8 pf;
      pf[0] = (bf16)plo[0]; pf[1] = (bf16)plo[1]; pf[2] = (bf16)plo[2]; pf[3] = (bf16)plo[3];
      pf[4] = (bf16)phi[0]; pf[5] = (bf16)phi[1]; pf[6] = (bf16)phi[2]; pf[7] = (bf16)phi[3];
      bf16x8 vf[4];
#pragma unroll
      for (int nd = 0; nd < 4; nd++)
        vf[nd] = *(const bf16x8*)(vt + (size_t)(nd * 16 + l16) * 1024 + kv0 + kkv * 32 + g * 8);
      __builtin_amdgcn_s_setprio(1);
#pragma unroll
      for (int nd = 0; nd < 4; nd++)
        oacc[nd] = __builtin_amdgcn_mfma_f32_16x16x32_bf16(vf[nd], pf, oacc[nd], 0, 0, 0);
      __builtin_amdgcn_s_setprio(0);
    }
    __syncthreads();   // all Pf reads done before next tile overwrites
  }

  // swapped PV layout: q = l16 axis, d = reg axis -> vectorized bf16x4 stores
  {
    const int q = q0 + w * 16 + l16;
    bf16* ob = aout + (size_t)(b * 1024 + q) * 768 + h * 64 + g * 4;
#pragma unroll
    for (int nd = 0; nd < 4; nd++) {
      bf16x4 o4;
      o4[0] = (bf16)oacc[nd][0]; o4[1] = (bf16)oacc[nd][1];
      o4[2] = (bf16)oacc[nd][2]; o4[3] = (bf16)oacc[nd][3];
      *(bf16x4*)(ob + nd * 16) = o4;
    }
  }
}

// ---------------- host ----------------
extern "C" void kernel_launch(void* const* d_in, const int* in_sizes, int n_in,
                              void* d_out, int out_size, void* d_ws, size_t ws_size,
                              hipStream_t stream) {
  (void)in_sizes; (void)n_in; (void)out_size; (void)ws_size;
  const float* x = (const float*)d_in[0];
#define IN(d, i) ((const float*)d_in[1 + (d) * 12 + (i)])
  float* outF = (float*)d_out;
  float* attnp[2] = {outF + 3145728, outF + 3145728 + 50331648};

  // 112 KiB dynamic LDS for the 256x192 GEMM (idempotent, capture-safe)
  const int kLds = 114688;
  hipFuncSetAttribute((const void*)gemm256_k<0, 3>,
                      hipFuncAttributeMaxDynamicSharedMemorySize, kLds);
  hipFuncSetAttribute((const void*)gemm256_k<1, 3>,
                      hipFuncAttributeMaxDynamicSharedMemorySize, kLds);
  hipFuncSetAttribute((const void*)gemm256_k<4, 3>,
                      hipFuncAttributeMaxDynamicSharedMemorySize, kLds);

  char* p = (char*)d_ws;
  auto alloc = [&](size_t bytes) { void* r = p; p += bytes; return r; };
  bf16 *qkv_wt[2], *proj_wt[2], *w1t[2], *w2t[2];
  for (int d = 0; d < 2; d++) {
    qkv_wt[d]  = (bf16*)alloc((size_t)2304 * 768 * 2);
    proj_wt[d] = (bf16*)alloc((size_t)768 * 768 * 2);
    w1t[d]     = (bf16*)alloc((size_t)3072 * 768 * 2);
    w2t[d]     = (bf16*)alloc((size_t)768 * 3072 * 2);
  }
  // hbuf+qkvb form one contiguous 25.17 MB region; reused as up to 4 bf16
  // split-K partials (4 x 3145728 elems) while both buffers are dead.
  bf16*  hbuf = (bf16*)alloc((size_t)4096 * 768 * 2);
  bf16*  qkvb = (bf16*)alloc((size_t)4096 * 2304 * 2);
  bf16*  pbuf = hbuf;
  bf16*  vT   = (bf16*)alloc((size_t)48 * 64 * 1024 * 2);
  bf16*  aout = (bf16*)alloc((size_t)4096 * 768 * 2);
  bf16*  hid  = (bf16*)alloc((size_t)4096 * 3072 * 2);
  float* xa   = (float*)alloc((size_t)4096 * 768 * 4);
  float* xb   = (float*)alloc((size_t)4096 * 768 * 4);

  transpose_all_k<<<14848, 256, 0, stream>>>(
      IN(0, 0), qkv_wt[0], IN(0, 2), proj_wt[0], IN(0, 8), w1t[0], IN(0, 10), w2t[0],
      IN(1, 0), qkv_wt[1], IN(1, 2), proj_wt[1], IN(1, 8), w1t[1], IN(1, 10), w2t[1],
      x, IN(0, 4), IN(0, 5), hbuf);

  // ---- layer 0 attention: xa = x + attn0(hbuf); also LN1_1(xa) -> hbuf ----
  gemm256_k<0, 3><<<dim3(12, 16), 512, kLds, stream>>>(hbuf, 768, qkv_wt[0], 768, IN(0, 1),
                                                       qkvb, 2304, 768, vT, 0);
  fattn_k<<<768, 256, 0, stream>>>(qkvb, vT, attnp[0], aout);
  gemm256_k<4, 3><<<dim3(4, 16, 4), 512, kLds, stream>>>(aout, 768, proj_wt[0], 768, nullptr,
                                                         pbuf, 768, 192, nullptr, 3145728);
  reduce_ln_k<4, 0, true><<<1024, 256, 0, stream>>>(pbuf, IN(0, 3), x, nullptr,
                                                    xa, IN(1, 4), IN(1, 5), hbuf);
  // ---- layer 1 attention: xb = xa + attn1(hbuf); also LN2_1(xb) -> hbuf ----
  gemm256_k<0, 3><<<dim3(12, 16), 512, kLds, stream>>>(hbuf, 768, qkv_wt[1], 768, IN(1, 1),
                                                       qkvb, 2304, 768, vT, 0);
  fattn_k<<<768, 256, 0, stream>>>(qkvb, vT, attnp[1], aout);
  gemm256_k<4, 3><<<dim3(4, 16, 4), 512, kLds, stream>>>(aout, 768, proj_wt[1], 768, nullptr,
                                                         pbuf, 768, 192, nullptr, 3145728);
  reduce_ln_k<4, 0, true><<<1024, 256, 0, stream>>>(pbuf, IN(1, 3), xa, nullptr,
                                                    xb, IN(1, 6), IN(1, 7), hbuf);
  // ---- layer 1 MLP + blend: xa = 0.5*(xa + xb + mlp1(hbuf)); LN2_0(xa) -> hbuf ----
  gemm256_k<1, 3><<<dim3(16, 16), 512, kLds, stream>>>(hbuf, 768, w1t[1], 768, IN(1, 9),
                                                       hid, 3072, 768, nullptr, 0);
  gemm256_k<4, 3><<<dim3(4, 16, 4), 512, kLds, stream>>>(hid, 3072, w2t[1], 3072, nullptr,
                                                         pbuf, 768, 768, nullptr, 3145728);
  reduce_ln_k<4, 1, true><<<1024, 256, 0, stream>>>(pbuf, IN(1, 11), xb, xa,
                                                    xa, IN(0, 6), IN(0, 7), hbuf);
  // ---- layer 0 MLP: out = xa + mlp0(hbuf) ----
  gemm256_k<1, 3><<<dim3(16, 16), 512, kLds, stream>>>(hbuf, 768, w1t[0], 768, IN(0, 9),
                                                       hid, 3072, 768, nullptr, 0);
  gemm256_k<4, 3><<<dim3(4, 16, 4), 512, kLds, stream>>>(hid, 3072, w2t[0], 3072, nullptr,
                                                         pbuf, 768, 768, nullptr, 3145728);
  reduce_ln_k<4, 0, false><<<1024, 256, 0, stream>>>(pbuf, IN(0, 11), xa, nullptr,
                                                     outF, nullptr, nullptr, nullptr);
#undef IN
}